// Round 1
// baseline (22591.853 us; speedup 1.0000x reference)
//
#include <hip/hip_runtime.h>
#include <hip/hip_cooperative_groups.h>
#include <cmath>

namespace cg = cooperative_groups;

#define LSEQ 256
#define BB_ 32
#define DD_ 768
#define HH_ 384
#define M_ (BB_*LSEQ)        // 8192
#define G4H 1536

__device__ __forceinline__ float sigf(float x) { return 1.0f / (1.0f + expf(-x)); }

// ---------------------------------------------------------------- embed + LN
__global__ __launch_bounds__(256) void embed_ln_k(
    const int* __restrict__ ids, const int* __restrict__ tts,
    const float* __restrict__ wemb, const float* __restrict__ pemb,
    const float* __restrict__ temb, const float* __restrict__ lng,
    const float* __restrict__ lnb, float* __restrict__ X)
{
    const int blt = blockIdx.x;          // b*256 + l
    const int l = blt & 255;
    const int tid = threadIdx.x;
    const int id = ids[blt];
    const int tt = tts[blt];
    const size_t wb = (size_t)id * DD_;
    float e0 = wemb[wb + tid]       + pemb[l*DD_ + tid]       + temb[tt*DD_ + tid];
    float e1 = wemb[wb + tid + 256] + pemb[l*DD_ + tid + 256] + temb[tt*DD_ + tid + 256];
    float e2 = wemb[wb + tid + 512] + pemb[l*DD_ + tid + 512] + temb[tt*DD_ + tid + 512];
    __shared__ float red[256];
    red[tid] = e0 + e1 + e2;
    __syncthreads();
    for (int off = 128; off; off >>= 1) { if (tid < off) red[tid] += red[tid+off]; __syncthreads(); }
    const float mu = red[0] * (1.0f/768.0f);
    __syncthreads();
    const float d0 = e0-mu, d1 = e1-mu, d2 = e2-mu;
    red[tid] = d0*d0 + d1*d1 + d2*d2;
    __syncthreads();
    for (int off = 128; off; off >>= 1) { if (tid < off) red[tid] += red[tid+off]; __syncthreads(); }
    const float var = red[0] * (1.0f/768.0f);
    const float rs = 1.0f / sqrtf(var + 1e-12f);
    float* xo = X + (size_t)blt * DD_;
    xo[tid]     = d0*rs*lng[tid]     + lnb[tid];
    xo[tid+256] = d1*rs*lng[tid+256] + lnb[tid+256];
    xo[tid+512] = d2*rs*lng[tid+512] + lnb[tid+512];
}

// ------------------------------------------------- GEMM: G[d][m][n] = X@Wih^T + bias
// M=8192, N=1536 per dir, K=768.  BM=128 BN=64 BK=16, 256 thr, 8x4 micro-tile.
__global__ __launch_bounds__(256) void gemm_xw_k(
    const float* __restrict__ X,    // [M][768]
    const float* __restrict__ Wih,  // [2][1536][768] (this layer)
    const float* __restrict__ b1,   // [2][1536]
    const float* __restrict__ b2,   // [2][1536]
    float* __restrict__ G)          // [2][M][1536]
{
    const int d  = blockIdx.z;
    const int m0 = blockIdx.x * 128;
    const int n0 = blockIdx.y * 64;
    const int tid = threadIdx.x;
    __shared__ float As[16][132];
    __shared__ float Bs[16][68];
    const int ty = tid >> 4;   // 0..15 -> rows ty*8..+7
    const int tx = tid & 15;   // 0..15 -> cols tx*4..+3
    float acc[8][4] = {};
    const float* Wd = Wih + (size_t)d * G4H * DD_;
    const int arow = tid >> 1, ahalf = tid & 1;
    const int brow = tid >> 2, bq = tid & 3;
    for (int k0 = 0; k0 < DD_; k0 += 16) {
        {
            const float* src = X + (size_t)(m0 + arow)*DD_ + k0 + ahalf*8;
            const float4 v0 = *(const float4*)src;
            const float4 v1 = *(const float4*)(src + 4);
            const int kk = ahalf*8;
            As[kk+0][arow]=v0.x; As[kk+1][arow]=v0.y; As[kk+2][arow]=v0.z; As[kk+3][arow]=v0.w;
            As[kk+4][arow]=v1.x; As[kk+5][arow]=v1.y; As[kk+6][arow]=v1.z; As[kk+7][arow]=v1.w;
        }
        {
            const float4 v = *(const float4*)(Wd + (size_t)(n0 + brow)*DD_ + k0 + bq*4);
            Bs[bq*4+0][brow]=v.x; Bs[bq*4+1][brow]=v.y; Bs[bq*4+2][brow]=v.z; Bs[bq*4+3][brow]=v.w;
        }
        __syncthreads();
        #pragma unroll
        for (int k = 0; k < 16; ++k) {
            const float4 a0 = *(const float4*)&As[k][ty*8];
            const float4 a1 = *(const float4*)&As[k][ty*8+4];
            const float4 bv = *(const float4*)&Bs[k][tx*4];
            const float ar[8] = {a0.x,a0.y,a0.z,a0.w,a1.x,a1.y,a1.z,a1.w};
            #pragma unroll
            for (int i = 0; i < 8; ++i) {
                acc[i][0] = fmaf(ar[i], bv.x, acc[i][0]);
                acc[i][1] = fmaf(ar[i], bv.y, acc[i][1]);
                acc[i][2] = fmaf(ar[i], bv.z, acc[i][2]);
                acc[i][3] = fmaf(ar[i], bv.w, acc[i][3]);
            }
        }
        __syncthreads();
    }
    const float* bb1 = b1 + d*G4H;
    const float* bb2 = b2 + d*G4H;
    #pragma unroll
    for (int i = 0; i < 8; ++i) {
        const int m = m0 + ty*8 + i;
        float* dst = G + ((size_t)d*M_ + m)*G4H + n0 + tx*4;
        #pragma unroll
        for (int j = 0; j < 4; ++j) {
            const int n = n0 + tx*4 + j;
            dst[j] = acc[i][j] + bb1[n] + bb2[n];
        }
    }
}

// ------------------------------------------------- LSTM recurrence (cooperative)
// grid 128: d = bid>>6, jb = bid&63 -> hidden units [jb*6, jb*6+6), 24 gate rows.
// thread: b = tid>>3 (0..31), rr = tid&7; rows rr, rr+8, rr+16 (row24 -> q=row24/6, jj=row24%6)
__global__ __launch_bounds__(256) void recur_k(
    const float* __restrict__ G,    // [2][M][1536] pre-gates (x@Wih^T + bih + bhh)
    const float* __restrict__ Whh,  // [2][1536][384] (this layer)
    float* __restrict__ Yout,       // [B][L][768]
    float* __restrict__ H)          // [2 parity][2 dir][32][384]
{
    cg::grid_group grid = cg::this_grid();
    const int bid = blockIdx.x;
    const int d  = bid >> 6;
    const int jb = bid & 63;
    const int j0 = jb * 6;
    const int tid = threadIdx.x;
    const int b  = tid >> 3;
    const int rr = tid & 7;

    __shared__ float w_s[24][388];
    __shared__ float gbuf[32][24];
    __shared__ float c_s[32*6];

    for (int idx = tid; idx < 24*384; idx += 256) {
        const int r = idx / 384, k = idx - r*384;
        const int n = (r/6)*384 + j0 + (r%6);
        w_s[r][k] = Whh[(size_t)d*G4H*HH_ + (size_t)n*HH_ + k];
    }
    if (tid < 192) c_s[tid] = 0.0f;
    __syncthreads();

    const int row0 = rr, row1 = rr+8, row2 = rr+16;
    const int n0 = (row0/6)*384 + j0 + (row0%6);
    const int n1 = (row1/6)*384 + j0 + (row1%6);
    const int n2 = (row2/6)*384 + j0 + (row2%6);

    for (int t = 0; t < LSEQ; ++t) {
        const int tt = d ? (LSEQ-1-t) : t;
        const size_t grow = ((size_t)d*M_ + (size_t)b*LSEQ + tt) * G4H;
        float a0 = G[grow + n0];
        float a1 = G[grow + n1];
        float a2 = G[grow + n2];
        if (t > 0) {
            const float* hp = H + ((((size_t)((t-1)&1))*2 + d)*32 + b)*HH_;
            #pragma unroll 8
            for (int k4 = 0; k4 < 96; ++k4) {
                const float4 h4 = *(const float4*)(hp + (k4<<2));
                const float4 w0 = *(const float4*)(&w_s[row0][k4<<2]);
                const float4 w1 = *(const float4*)(&w_s[row1][k4<<2]);
                const float4 w2 = *(const float4*)(&w_s[row2][k4<<2]);
                a0 = fmaf(h4.x,w0.x,fmaf(h4.y,w0.y,fmaf(h4.z,w0.z,fmaf(h4.w,w0.w,a0))));
                a1 = fmaf(h4.x,w1.x,fmaf(h4.y,w1.y,fmaf(h4.z,w1.z,fmaf(h4.w,w1.w,a1))));
                a2 = fmaf(h4.x,w2.x,fmaf(h4.y,w2.y,fmaf(h4.z,w2.z,fmaf(h4.w,w2.w,a2))));
            }
        }
        gbuf[b][row0] = a0; gbuf[b][row1] = a1; gbuf[b][row2] = a2;
        __syncthreads();
        if (tid < 192) {
            const int bb = tid / 6, jj = tid - bb*6;
            const float gi = gbuf[bb][jj];
            const float gf = gbuf[bb][6+jj];
            const float gg = gbuf[bb][12+jj];
            const float go = gbuf[bb][18+jj];
            const float c = sigf(gf)*c_s[tid] + sigf(gi)*tanhf(gg);
            const float h = sigf(go)*tanhf(c);
            c_s[tid] = c;
            H[((((size_t)(t&1))*2 + d)*32 + bb)*HH_ + j0 + jj] = h;
            Yout[((size_t)bb*LSEQ + tt)*DD_ + d*HH_ + j0 + jj] = h;
        }
        __threadfence();
        grid.sync();
    }
}

// ------------------------------------------------- compaction scan
__global__ __launch_bounds__(256) void scan_k(
    const int* __restrict__ valid, const int* __restrict__ lmask,
    int* __restrict__ dest, int* __restrict__ nvm)
{
    const int b = blockIdx.x, l = threadIdx.x;
    __shared__ int arr[256];
    __shared__ int ms[256];
    arr[l] = valid[b*256 + l];
    ms[l]  = lmask[b*256 + l];
    __syncthreads();
    for (int off = 1; off < 256; off <<= 1) {
        const int add = arr[l] + ((l >= off) ? arr[l-off] : 0);
        __syncthreads();
        arr[l] = add;
        __syncthreads();
    }
    dest[b*256 + l] = arr[l] - 1;
    for (int off = 128; off; off >>= 1) { if (l < off) ms[l] += ms[l+off]; __syncthreads(); }
    if (l == 0) nvm[b] = ms[0];
}

__global__ __launch_bounds__(256) void scatter_k(
    const int* __restrict__ valid, const int* __restrict__ dest,
    const float* __restrict__ S, float* __restrict__ V)
{
    const int blt = blockIdx.x;
    if (!valid[blt]) return;
    const int b = blt >> 8;
    const int dd = dest[blt];
    const int tid = threadIdx.x;
    const float* src = S + (size_t)blt * DD_;
    float* dst = V + ((size_t)(b*256 + dd)) * DD_;
    dst[tid] = src[tid]; dst[tid+256] = src[tid+256]; dst[tid+512] = src[tid+512];
}

// ------------------------------------------------- heads: logits (wave per row)
__global__ __launch_bounds__(256) void heads_k(
    const float* __restrict__ V,
    const float* __restrict__ pW, const float* __restrict__ pb,
    const float* __restrict__ cW, const float* __restrict__ cb,
    float* __restrict__ PL, float* __restrict__ CL)
{
    const int w = threadIdx.x >> 6, lane = threadIdx.x & 63;
    const int m = blockIdx.x*4 + w;
    const float* vr = V + (size_t)m * DD_;
    float ap[9] = {}; float ac[3] = {};
    #pragma unroll
    for (int kk = 0; kk < 12; ++kk) {
        const int k = kk*64 + lane;
        const float v = vr[k];
        #pragma unroll
        for (int o = 0; o < 9; ++o) ap[o] = fmaf(v, pW[o*DD_ + k], ap[o]);
        #pragma unroll
        for (int o = 0; o < 3; ++o) ac[o] = fmaf(v, cW[o*DD_ + k], ac[o]);
    }
    #pragma unroll
    for (int o = 0; o < 9; ++o) {
        float r = ap[o];
        for (int off = 32; off; off >>= 1) r += __shfl_down(r, off);
        if (lane == 0) PL[(size_t)m*9 + o] = r + pb[o];
    }
    #pragma unroll
    for (int o = 0; o < 3; ++o) {
        float r = ac[o];
        for (int off = 32; off; off >>= 1) r += __shfl_down(r, off);
        if (lane == 0) CL[(size_t)m*3 + o] = r + cb[o];
    }
}

// ------------------------------------------------- CRF log-likelihood (wave per b)
template<int NT>
__global__ __launch_bounds__(64) void crf_ll_k(
    const float* __restrict__ E, const int* __restrict__ tg,
    const int* __restrict__ nvm,
    const float* __restrict__ st, const float* __restrict__ en,
    const float* __restrict__ tr, float* __restrict__ llout)
{
    const int b = blockIdx.x;
    const int lane = threadIdx.x;
    const int nv = nvm[b];
    const int base = b*256;
    float num = 0.0f;
    for (int t = lane; t < nv; t += 64) {
        const int tgt = tg[base + t];
        float c = E[(size_t)(base + t)*NT + tgt];
        if (t > 0) c += tr[tg[base + t - 1]*NT + tgt];
        num += c;
    }
    for (int off = 32; off; off >>= 1) num += __shfl_down(num, off);

    float trc[NT];
    float s;
    if (lane < NT) {
        #pragma unroll
        for (int i = 0; i < NT; ++i) trc[i] = tr[i*NT + lane];
        s = st[lane] + E[(size_t)base*NT + lane];
    } else {
        #pragma unroll
        for (int i = 0; i < NT; ++i) trc[i] = 0.0f;
        s = -INFINITY;
    }
    for (int t = 1; t < nv; ++t) {
        float si[NT];
        #pragma unroll
        for (int i = 0; i < NT; ++i) si[i] = __shfl(s, i) + trc[i];
        float m = si[0];
        #pragma unroll
        for (int i = 1; i < NT; ++i) m = fmaxf(m, si[i]);
        float sum = 0.0f;
        #pragma unroll
        for (int i = 0; i < NT; ++i) sum += expf(si[i] - m);
        if (lane < NT) s = m + logf(sum) + E[(size_t)(base + t)*NT + lane];
    }
    float v = (lane < NT) ? s + en[lane] : -INFINITY;
    float mx = v;
    for (int off = 32; off; off >>= 1) mx = fmaxf(mx, __shfl_xor(mx, off));
    float ex = (lane < NT) ? expf(v - mx) : 0.0f;
    for (int off = 32; off; off >>= 1) ex += __shfl_xor(ex, off);
    const float logZ = mx + logf(ex);
    if (lane == 0) {
        num += st[tg[base]] + en[tg[base + nv - 1]];
        llout[b] = num - logZ;
    }
}

// ------------------------------------------------- Viterbi decode (wave per b)
template<int NT>
__global__ __launch_bounds__(64) void viterbi_k(
    const float* __restrict__ E, const int* __restrict__ nvm,
    const float* __restrict__ st, const float* __restrict__ en,
    const float* __restrict__ tr, float* __restrict__ outp)
{
    const int b = blockIdx.x;
    const int lane = threadIdx.x;
    const int nv = nvm[b];
    const int base = b*256;
    float* o = outp + base;
    __shared__ unsigned char hist[256][16];
    float trc[NT];
    float s;
    if (lane < NT) {
        #pragma unroll
        for (int i = 0; i < NT; ++i) trc[i] = tr[i*NT + lane];
        s = st[lane] + E[(size_t)base*NT + lane];
    } else {
        #pragma unroll
        for (int i = 0; i < NT; ++i) trc[i] = 0.0f;
        s = -INFINITY;
    }
    for (int t = 1; t < nv; ++t) {
        float si[NT];
        #pragma unroll
        for (int i = 0; i < NT; ++i) si[i] = __shfl(s, i) + trc[i];
        float best = si[0];
        int bi = 0;
        #pragma unroll
        for (int i = 1; i < NT; ++i) if (si[i] > best) { best = si[i]; bi = i; }
        if (lane < NT) {
            hist[t][lane] = (unsigned char)bi;
            s = best + E[(size_t)(base + t)*NT + lane];
        }
    }
    float v = (lane < NT) ? s + en[lane] : -INFINITY;
    int idx = lane;
    for (int off = 32; off; off >>= 1) {
        const float ov = __shfl_xor(v, off);
        const int   oi = __shfl_xor(idx, off);
        if (ov > v || (ov == v && oi < idx)) { v = ov; idx = oi; }
    }
    __syncthreads();
    if (lane == 0) {
        int tag = idx;
        o[nv-1] = (float)tag;
        for (int t = nv - 1; t >= 1; --t) {
            tag = hist[t][tag];
            o[t-1] = (float)tag;
        }
    }
    for (int t = nv + lane; t < 256; t += 64) o[t] = 0.0f;
}

__global__ __launch_bounds__(64) void finalize_k(const float* __restrict__ llb,
                                                 float* __restrict__ out)
{
    const int lane = threadIdx.x;
    const float v = llb[lane];
    float p = (lane < 32) ? v : 0.0f;
    float c = (lane < 32) ? 0.0f : v;
    for (int off = 32; off; off >>= 1) { p += __shfl_down(p, off); c += __shfl_down(c, off); }
    if (lane == 0) { out[0] = -(p + c); out[1] = p; out[2] = c; }
}

// ================================================================ host
extern "C" void kernel_launch(void* const* d_in, const int* in_sizes, int n_in,
                              void* d_out, int out_size, void* d_ws, size_t ws_size,
                              hipStream_t stream) {
    const int*   input_ids = (const int*)d_in[0];
    const int*   tt_ids    = (const int*)d_in[1];
    const int*   valid     = (const int*)d_in[2];
    const int*   plab      = (const int*)d_in[3];
    const int*   clab      = (const int*)d_in[4];
    const int*   lmask     = (const int*)d_in[5];
    const float* wemb      = (const float*)d_in[6];
    const float* pemb      = (const float*)d_in[7];
    const float* temb      = (const float*)d_in[8];
    const float* ln_g      = (const float*)d_in[9];
    const float* ln_b      = (const float*)d_in[10];
    const float* Wih       = (const float*)d_in[11];
    const float* Whh       = (const float*)d_in[12];
    const float* bih       = (const float*)d_in[13];
    const float* bhh       = (const float*)d_in[14];
    const float* pW        = (const float*)d_in[15];
    const float* pb        = (const float*)d_in[16];
    const float* cW        = (const float*)d_in[17];
    const float* cb        = (const float*)d_in[18];
    const float* p_start   = (const float*)d_in[19];
    const float* p_end     = (const float*)d_in[20];
    const float* p_trans   = (const float*)d_in[21];
    const float* c_start   = (const float*)d_in[22];
    const float* c_end     = (const float*)d_in[23];
    const float* c_trans   = (const float*)d_in[24];

    float* ws = (float*)d_ws;
    float* X   = ws;                       // 6,291,456
    float* Y   = X  + 6291456;             // 6,291,456
    float* Gb  = Y  + 6291456;             // 25,165,824
    float* V   = Gb + 25165824;            // 6,291,456
    float* PL  = V  + 6291456;             // 73,728
    float* CL  = PL + 73728;               // 24,576
    float* Hb  = CL + 24576;               // 98,304
    float* llb = Hb + 98304;               // 64
    int*   destb = (int*)(llb + 64);       // 8192 ints
    int*   nvm   = destb + 8192;           // 32 ints
    float* out = (float*)d_out;

    embed_ln_k<<<8192, 256, 0, stream>>>(input_ids, tt_ids, wemb, pemb, temb, ln_g, ln_b, X);

    for (int layer = 0; layer < 2; ++layer) {
        const float* Xin  = layer ? Y : X;
        float*       Yout = layer ? X : Y;
        const float* Wl  = Wih + (size_t)layer * 2 * G4H * DD_;
        const float* Whl = Whh + (size_t)layer * 2 * G4H * HH_;
        const float* b1  = bih + (size_t)layer * 2 * G4H;
        const float* b2  = bhh + (size_t)layer * 2 * G4H;
        gemm_xw_k<<<dim3(64, 24, 2), 256, 0, stream>>>(Xin, Wl, b1, b2, Gb);
        const float* gA = Gb; const float* wA = Whl; float* yA = Yout; float* hA = Hb;
        void* kargs[] = { (void*)&gA, (void*)&wA, (void*)&yA, (void*)&hA };
        hipLaunchCooperativeKernel((const void*)recur_k, dim3(128), dim3(256), kargs, 0, stream);
    }

    scan_k<<<32, 256, 0, stream>>>(valid, lmask, destb, nvm);
    hipMemsetAsync(V, 0, (size_t)6291456 * 4, stream);
    scatter_k<<<8192, 256, 0, stream>>>(valid, destb, X, V);   // final seq is in X
    heads_k<<<2048, 256, 0, stream>>>(V, pW, pb, cW, cb, PL, CL);

    crf_ll_k<9><<<32, 64, 0, stream>>>(PL, plab, nvm, p_start, p_end, p_trans, llb);
    crf_ll_k<3><<<32, 64, 0, stream>>>(CL, clab, nvm, c_start, c_end, c_trans, llb + 32);
    viterbi_k<9><<<32, 64, 0, stream>>>(PL, nvm, p_start, p_end, p_trans, out + 3);
    viterbi_k<3><<<32, 64, 0, stream>>>(CL, nvm, c_start, c_end, c_trans, out + 3 + 8192);
    finalize_k<<<1, 64, 0, stream>>>(llb, out);
}

// Round 2
// 20185.481 us; speedup vs baseline: 1.1192x; 1.1192x over previous
//
#include <hip/hip_runtime.h>
#include <cmath>

#define LSEQ 256
#define BB_ 32
#define DD_ 768
#define HH_ 384
#define M_ (BB_*LSEQ)        // 8192
#define G4H 1536

__device__ __forceinline__ float sigf(float x) { return 1.0f / (1.0f + expf(-x)); }

// ---------------------------------------------------------------- embed + LN
__global__ __launch_bounds__(256) void embed_ln_k(
    const int* __restrict__ ids, const int* __restrict__ tts,
    const float* __restrict__ wemb, const float* __restrict__ pemb,
    const float* __restrict__ temb, const float* __restrict__ lng,
    const float* __restrict__ lnb, float* __restrict__ X)
{
    const int blt = blockIdx.x;          // b*256 + l
    const int l = blt & 255;
    const int tid = threadIdx.x;
    const int id = ids[blt];
    const int tt = tts[blt];
    const size_t wb = (size_t)id * DD_;
    float e0 = wemb[wb + tid]       + pemb[l*DD_ + tid]       + temb[tt*DD_ + tid];
    float e1 = wemb[wb + tid + 256] + pemb[l*DD_ + tid + 256] + temb[tt*DD_ + tid + 256];
    float e2 = wemb[wb + tid + 512] + pemb[l*DD_ + tid + 512] + temb[tt*DD_ + tid + 512];
    __shared__ float red[256];
    red[tid] = e0 + e1 + e2;
    __syncthreads();
    for (int off = 128; off; off >>= 1) { if (tid < off) red[tid] += red[tid+off]; __syncthreads(); }
    const float mu = red[0] * (1.0f/768.0f);
    __syncthreads();
    const float d0 = e0-mu, d1 = e1-mu, d2 = e2-mu;
    red[tid] = d0*d0 + d1*d1 + d2*d2;
    __syncthreads();
    for (int off = 128; off; off >>= 1) { if (tid < off) red[tid] += red[tid+off]; __syncthreads(); }
    const float var = red[0] * (1.0f/768.0f);
    const float rs = 1.0f / sqrtf(var + 1e-12f);
    float* xo = X + (size_t)blt * DD_;
    xo[tid]     = d0*rs*lng[tid]     + lnb[tid];
    xo[tid+256] = d1*rs*lng[tid+256] + lnb[tid+256];
    xo[tid+512] = d2*rs*lng[tid+512] + lnb[tid+512];
}

// ------------------------------------------------- GEMM: G[d][m][n] = X@Wih^T + bias
__global__ __launch_bounds__(256) void gemm_xw_k(
    const float* __restrict__ X,    // [M][768]
    const float* __restrict__ Wih,  // [2][1536][768] (this layer)
    const float* __restrict__ b1,   // [2][1536]
    const float* __restrict__ b2,   // [2][1536]
    float* __restrict__ G)          // [2][M][1536]
{
    const int d  = blockIdx.z;
    const int m0 = blockIdx.x * 128;
    const int n0 = blockIdx.y * 64;
    const int tid = threadIdx.x;
    __shared__ float As[16][132];
    __shared__ float Bs[16][68];
    const int ty = tid >> 4;
    const int tx = tid & 15;
    float acc[8][4] = {};
    const float* Wd = Wih + (size_t)d * G4H * DD_;
    const int arow = tid >> 1, ahalf = tid & 1;
    const int brow = tid >> 2, bq = tid & 3;
    for (int k0 = 0; k0 < DD_; k0 += 16) {
        {
            const float* src = X + (size_t)(m0 + arow)*DD_ + k0 + ahalf*8;
            const float4 v0 = *(const float4*)src;
            const float4 v1 = *(const float4*)(src + 4);
            const int kk = ahalf*8;
            As[kk+0][arow]=v0.x; As[kk+1][arow]=v0.y; As[kk+2][arow]=v0.z; As[kk+3][arow]=v0.w;
            As[kk+4][arow]=v1.x; As[kk+5][arow]=v1.y; As[kk+6][arow]=v1.z; As[kk+7][arow]=v1.w;
        }
        {
            const float4 v = *(const float4*)(Wd + (size_t)(n0 + brow)*DD_ + k0 + bq*4);
            Bs[bq*4+0][brow]=v.x; Bs[bq*4+1][brow]=v.y; Bs[bq*4+2][brow]=v.z; Bs[bq*4+3][brow]=v.w;
        }
        __syncthreads();
        #pragma unroll
        for (int k = 0; k < 16; ++k) {
            const float4 a0 = *(const float4*)&As[k][ty*8];
            const float4 a1 = *(const float4*)&As[k][ty*8+4];
            const float4 bv = *(const float4*)&Bs[k][tx*4];
            const float ar[8] = {a0.x,a0.y,a0.z,a0.w,a1.x,a1.y,a1.z,a1.w};
            #pragma unroll
            for (int i = 0; i < 8; ++i) {
                acc[i][0] = fmaf(ar[i], bv.x, acc[i][0]);
                acc[i][1] = fmaf(ar[i], bv.y, acc[i][1]);
                acc[i][2] = fmaf(ar[i], bv.z, acc[i][2]);
                acc[i][3] = fmaf(ar[i], bv.w, acc[i][3]);
            }
        }
        __syncthreads();
    }
    const float* bb1 = b1 + d*G4H;
    const float* bb2 = b2 + d*G4H;
    #pragma unroll
    for (int i = 0; i < 8; ++i) {
        const int m = m0 + ty*8 + i;
        float* dst = G + ((size_t)d*M_ + m)*G4H + n0 + tx*4;
        #pragma unroll
        for (int j = 0; j < 4; ++j) {
            const int n = n0 + tx*4 + j;
            dst[j] = acc[i][j] + bb1[n] + bb2[n];
        }
    }
}

// ------------------------------------------------- LSTM recurrence (custom barrier)
// grid 128: d = bid>>6, jb = bid&63 -> hidden units [jb*6, jb*6+6), 24 gate rows.
// Barrier: per-dir monotonic counter (64 arrivals/step), AGENT-scope atomics.
__global__ __launch_bounds__(256) void recur_k(
    const float* __restrict__ G,    // [2][M][1536] pre-gates
    const float* __restrict__ Whh,  // [2][1536][384] (this layer)
    float* __restrict__ Yout,       // [B][L][768]
    float* __restrict__ H,          // [2 parity][2 dir][32][384]
    unsigned* __restrict__ bar)     // [2 dirs x 32 stride]
{
    const int bid = blockIdx.x;
    const int d  = bid >> 6;
    const int jb = bid & 63;
    const int j0 = jb * 6;
    const int tid = threadIdx.x;
    const int b  = tid >> 3;
    const int rr = tid & 7;
    unsigned* cnt = bar + d*32;     // 128B apart per dir

    __shared__ float w_s[24][388];
    __shared__ float gbuf[32][24];
    __shared__ float c_s[32*6];

    for (int idx = tid; idx < 24*384; idx += 256) {
        const int r = idx / 384, k = idx - r*384;
        const int n = (r/6)*384 + j0 + (r%6);
        w_s[r][k] = Whh[(size_t)d*G4H*HH_ + (size_t)n*HH_ + k];
    }
    if (tid < 192) c_s[tid] = 0.0f;
    __syncthreads();

    const int row0 = rr, row1 = rr+8, row2 = rr+16;
    const int n0 = (row0/6)*384 + j0 + (row0%6);
    const int n1 = (row1/6)*384 + j0 + (row1%6);
    const int n2 = (row2/6)*384 + j0 + (row2%6);

    // t = 0 pre-gates
    const int tt0 = d ? (LSEQ-1) : 0;
    size_t grow = ((size_t)d*M_ + (size_t)b*LSEQ + tt0) * G4H;
    float a0 = G[grow + n0];
    float a1 = G[grow + n1];
    float a2 = G[grow + n2];

    for (int t = 0; t < LSEQ; ++t) {
        if (t > 0) {
            const float* hp = H + ((((size_t)((t-1)&1))*2 + d)*32 + b)*HH_;
            #pragma unroll 8
            for (int k4 = 0; k4 < 96; ++k4) {
                const float4 h4 = *(const float4*)(hp + (k4<<2));
                const float4 w0 = *(const float4*)(&w_s[row0][k4<<2]);
                const float4 w1 = *(const float4*)(&w_s[row1][k4<<2]);
                const float4 w2 = *(const float4*)(&w_s[row2][k4<<2]);
                a0 = fmaf(h4.x,w0.x,fmaf(h4.y,w0.y,fmaf(h4.z,w0.z,fmaf(h4.w,w0.w,a0))));
                a1 = fmaf(h4.x,w1.x,fmaf(h4.y,w1.y,fmaf(h4.z,w1.z,fmaf(h4.w,w1.w,a1))));
                a2 = fmaf(h4.x,w2.x,fmaf(h4.y,w2.y,fmaf(h4.z,w2.z,fmaf(h4.w,w2.w,a2))));
            }
        }
        gbuf[b][row0] = a0; gbuf[b][row1] = a1; gbuf[b][row2] = a2;
        __syncthreads();

        // prefetch next step's pre-gates (independent of h) — hides HBM under barrier
        if (t + 1 < LSEQ) {
            const int ttn = d ? (LSEQ-2-t) : (t+1);
            grow = ((size_t)d*M_ + (size_t)b*LSEQ + ttn) * G4H;
            a0 = G[grow + n0];
            a1 = G[grow + n1];
            a2 = G[grow + n2];
        }

        if (tid < 192) {
            const int bb = tid / 6, jj = tid - bb*6;
            const float gi = gbuf[bb][jj];
            const float gf = gbuf[bb][6+jj];
            const float gg = gbuf[bb][12+jj];
            const float go = gbuf[bb][18+jj];
            const float c = sigf(gf)*c_s[tid] + sigf(gi)*tanhf(gg);
            const float h = sigf(go)*tanhf(c);
            c_s[tid] = c;
            H[((((size_t)(t&1))*2 + d)*32 + bb)*HH_ + j0 + jj] = h;
            Yout[((size_t)bb*LSEQ + ((d ? (LSEQ-1-t) : t)))*DD_ + d*HH_ + j0 + jj] = h;
        }

        if (t + 1 < LSEQ) {
            __threadfence();
            __syncthreads();
            if (tid == 0) {
                __hip_atomic_fetch_add(cnt, 1u, __ATOMIC_RELEASE, __HIP_MEMORY_SCOPE_AGENT);
                const unsigned target = (unsigned)(t + 1) * 64u;
                while (__hip_atomic_load(cnt, __ATOMIC_ACQUIRE, __HIP_MEMORY_SCOPE_AGENT) < target) {
                    __builtin_amdgcn_s_sleep(1);
                }
            }
            __syncthreads();
            __threadfence();
        }
    }
}

// ------------------------------------------------- compaction scan
__global__ __launch_bounds__(256) void scan_k(
    const int* __restrict__ valid, const int* __restrict__ lmask,
    int* __restrict__ dest, int* __restrict__ nvm)
{
    const int b = blockIdx.x, l = threadIdx.x;
    __shared__ int arr[256];
    __shared__ int ms[256];
    arr[l] = valid[b*256 + l];
    ms[l]  = lmask[b*256 + l];
    __syncthreads();
    for (int off = 1; off < 256; off <<= 1) {
        const int add = arr[l] + ((l >= off) ? arr[l-off] : 0);
        __syncthreads();
        arr[l] = add;
        __syncthreads();
    }
    dest[b*256 + l] = arr[l] - 1;
    for (int off = 128; off; off >>= 1) { if (l < off) ms[l] += ms[l+off]; __syncthreads(); }
    if (l == 0) nvm[b] = ms[0];
}

__global__ __launch_bounds__(256) void scatter_k(
    const int* __restrict__ valid, const int* __restrict__ dest,
    const float* __restrict__ S, float* __restrict__ V)
{
    const int blt = blockIdx.x;
    if (!valid[blt]) return;
    const int b = blt >> 8;
    const int dd = dest[blt];
    const int tid = threadIdx.x;
    const float* src = S + (size_t)blt * DD_;
    float* dst = V + ((size_t)(b*256 + dd)) * DD_;
    dst[tid] = src[tid]; dst[tid+256] = src[tid+256]; dst[tid+512] = src[tid+512];
}

// ------------------------------------------------- heads: logits (wave per row)
__global__ __launch_bounds__(256) void heads_k(
    const float* __restrict__ V,
    const float* __restrict__ pW, const float* __restrict__ pb,
    const float* __restrict__ cW, const float* __restrict__ cb,
    float* __restrict__ PL, float* __restrict__ CL)
{
    const int w = threadIdx.x >> 6, lane = threadIdx.x & 63;
    const int m = blockIdx.x*4 + w;
    const float* vr = V + (size_t)m * DD_;
    float ap[9] = {}; float ac[3] = {};
    #pragma unroll
    for (int kk = 0; kk < 12; ++kk) {
        const int k = kk*64 + lane;
        const float v = vr[k];
        #pragma unroll
        for (int o = 0; o < 9; ++o) ap[o] = fmaf(v, pW[o*DD_ + k], ap[o]);
        #pragma unroll
        for (int o = 0; o < 3; ++o) ac[o] = fmaf(v, cW[o*DD_ + k], ac[o]);
    }
    #pragma unroll
    for (int o = 0; o < 9; ++o) {
        float r = ap[o];
        for (int off = 32; off; off >>= 1) r += __shfl_down(r, off);
        if (lane == 0) PL[(size_t)m*9 + o] = r + pb[o];
    }
    #pragma unroll
    for (int o = 0; o < 3; ++o) {
        float r = ac[o];
        for (int off = 32; off; off >>= 1) r += __shfl_down(r, off);
        if (lane == 0) CL[(size_t)m*3 + o] = r + cb[o];
    }
}

// ------------------------------------------------- CRF log-likelihood (wave per b)
template<int NT>
__global__ __launch_bounds__(64) void crf_ll_k(
    const float* __restrict__ E, const int* __restrict__ tg,
    const int* __restrict__ nvm,
    const float* __restrict__ st, const float* __restrict__ en,
    const float* __restrict__ tr, float* __restrict__ llout)
{
    const int b = blockIdx.x;
    const int lane = threadIdx.x;
    const int nv = nvm[b];
    const int base = b*256;
    float num = 0.0f;
    for (int t = lane; t < nv; t += 64) {
        const int tgt = tg[base + t];
        float c = E[(size_t)(base + t)*NT + tgt];
        if (t > 0) c += tr[tg[base + t - 1]*NT + tgt];
        num += c;
    }
    for (int off = 32; off; off >>= 1) num += __shfl_down(num, off);

    float trc[NT];
    float s;
    if (lane < NT) {
        #pragma unroll
        for (int i = 0; i < NT; ++i) trc[i] = tr[i*NT + lane];
        s = st[lane] + E[(size_t)base*NT + lane];
    } else {
        #pragma unroll
        for (int i = 0; i < NT; ++i) trc[i] = 0.0f;
        s = -INFINITY;
    }
    for (int t = 1; t < nv; ++t) {
        float si[NT];
        #pragma unroll
        for (int i = 0; i < NT; ++i) si[i] = __shfl(s, i) + trc[i];
        float m = si[0];
        #pragma unroll
        for (int i = 1; i < NT; ++i) m = fmaxf(m, si[i]);
        float sum = 0.0f;
        #pragma unroll
        for (int i = 0; i < NT; ++i) sum += expf(si[i] - m);
        if (lane < NT) s = m + logf(sum) + E[(size_t)(base + t)*NT + lane];
    }
    float v = (lane < NT) ? s + en[lane] : -INFINITY;
    float mx = v;
    for (int off = 32; off; off >>= 1) mx = fmaxf(mx, __shfl_xor(mx, off));
    float ex = (lane < NT) ? expf(v - mx) : 0.0f;
    for (int off = 32; off; off >>= 1) ex += __shfl_xor(ex, off);
    const float logZ = mx + logf(ex);
    if (lane == 0) {
        num += st[tg[base]] + en[tg[base + nv - 1]];
        llout[b] = num - logZ;
    }
}

// ------------------------------------------------- Viterbi decode (wave per b)
template<int NT>
__global__ __launch_bounds__(64) void viterbi_k(
    const float* __restrict__ E, const int* __restrict__ nvm,
    const float* __restrict__ st, const float* __restrict__ en,
    const float* __restrict__ tr, float* __restrict__ outp)
{
    const int b = blockIdx.x;
    const int lane = threadIdx.x;
    const int nv = nvm[b];
    const int base = b*256;
    float* o = outp + base;
    __shared__ unsigned char hist[256][16];
    float trc[NT];
    float s;
    if (lane < NT) {
        #pragma unroll
        for (int i = 0; i < NT; ++i) trc[i] = tr[i*NT + lane];
        s = st[lane] + E[(size_t)base*NT + lane];
    } else {
        #pragma unroll
        for (int i = 0; i < NT; ++i) trc[i] = 0.0f;
        s = -INFINITY;
    }
    for (int t = 1; t < nv; ++t) {
        float si[NT];
        #pragma unroll
        for (int i = 0; i < NT; ++i) si[i] = __shfl(s, i) + trc[i];
        float best = si[0];
        int bi = 0;
        #pragma unroll
        for (int i = 1; i < NT; ++i) if (si[i] > best) { best = si[i]; bi = i; }
        if (lane < NT) {
            hist[t][lane] = (unsigned char)bi;
            s = best + E[(size_t)(base + t)*NT + lane];
        }
    }
    float v = (lane < NT) ? s + en[lane] : -INFINITY;
    int idx = lane;
    for (int off = 32; off; off >>= 1) {
        const float ov = __shfl_xor(v, off);
        const int   oi = __shfl_xor(idx, off);
        if (ov > v || (ov == v && oi < idx)) { v = ov; idx = oi; }
    }
    __syncthreads();
    if (lane == 0) {
        int tag = idx;
        o[nv-1] = (float)tag;
        for (int t = nv - 1; t >= 1; --t) {
            tag = hist[t][tag];
            o[t-1] = (float)tag;
        }
    }
    for (int t = nv + lane; t < 256; t += 64) o[t] = 0.0f;
}

__global__ __launch_bounds__(64) void finalize_k(const float* __restrict__ llb,
                                                 float* __restrict__ out)
{
    const int lane = threadIdx.x;
    const float v = llb[lane];
    float p = (lane < 32) ? v : 0.0f;
    float c = (lane < 32) ? 0.0f : v;
    for (int off = 32; off; off >>= 1) { p += __shfl_down(p, off); c += __shfl_down(c, off); }
    if (lane == 0) { out[0] = -(p + c); out[1] = p; out[2] = c; }
}

// ================================================================ host
extern "C" void kernel_launch(void* const* d_in, const int* in_sizes, int n_in,
                              void* d_out, int out_size, void* d_ws, size_t ws_size,
                              hipStream_t stream) {
    const int*   input_ids = (const int*)d_in[0];
    const int*   tt_ids    = (const int*)d_in[1];
    const int*   valid     = (const int*)d_in[2];
    const int*   plab      = (const int*)d_in[3];
    const int*   clab      = (const int*)d_in[4];
    const int*   lmask     = (const int*)d_in[5];
    const float* wemb      = (const float*)d_in[6];
    const float* pemb      = (const float*)d_in[7];
    const float* temb      = (const float*)d_in[8];
    const float* ln_g      = (const float*)d_in[9];
    const float* ln_b      = (const float*)d_in[10];
    const float* Wih       = (const float*)d_in[11];
    const float* Whh       = (const float*)d_in[12];
    const float* bih       = (const float*)d_in[13];
    const float* bhh       = (const float*)d_in[14];
    const float* pW        = (const float*)d_in[15];
    const float* pb        = (const float*)d_in[16];
    const float* cW        = (const float*)d_in[17];
    const float* cb        = (const float*)d_in[18];
    const float* p_start   = (const float*)d_in[19];
    const float* p_end     = (const float*)d_in[20];
    const float* p_trans   = (const float*)d_in[21];
    const float* c_start   = (const float*)d_in[22];
    const float* c_end     = (const float*)d_in[23];
    const float* c_trans   = (const float*)d_in[24];

    float* ws = (float*)d_ws;
    float* X   = ws;                       // 6,291,456
    float* Y   = X  + 6291456;             // 6,291,456
    float* Gb  = Y  + 6291456;             // 25,165,824
    float* V   = Gb + 25165824;            // 6,291,456
    float* PL  = V  + 6291456;             // 73,728
    float* CL  = PL + 73728;               // 24,576
    float* Hb  = CL + 24576;               // 98,304
    float* llb = Hb + 98304;               // 64
    int*   destb = (int*)(llb + 64);       // 8192 ints
    int*   nvm   = destb + 8192;           // 32 ints
    unsigned* bar = (unsigned*)(nvm + 32); // 2 layers x 2 dirs x 32-uint stride
    float* out = (float*)d_out;

    embed_ln_k<<<8192, 256, 0, stream>>>(input_ids, tt_ids, wemb, pemb, temb, ln_g, ln_b, X);
    hipMemsetAsync(bar, 0, 512, stream);

    for (int layer = 0; layer < 2; ++layer) {
        const float* Xin  = layer ? Y : X;
        float*       Yout = layer ? X : Y;
        const float* Wl  = Wih + (size_t)layer * 2 * G4H * DD_;
        const float* Whl = Whh + (size_t)layer * 2 * G4H * HH_;
        const float* b1  = bih + (size_t)layer * 2 * G4H;
        const float* b2  = bhh + (size_t)layer * 2 * G4H;
        gemm_xw_k<<<dim3(64, 24, 2), 256, 0, stream>>>(Xin, Wl, b1, b2, Gb);
        const float* gA = Gb; const float* wA = Whl; float* yA = Yout; float* hA = Hb;
        unsigned* barA = bar + layer*64;
        void* kargs[] = { (void*)&gA, (void*)&wA, (void*)&yA, (void*)&hA, (void*)&barA };
        hipLaunchCooperativeKernel((const void*)recur_k, dim3(128), dim3(256), kargs, 0, stream);
    }

    scan_k<<<32, 256, 0, stream>>>(valid, lmask, destb, nvm);
    hipMemsetAsync(V, 0, (size_t)6291456 * 4, stream);
    scatter_k<<<8192, 256, 0, stream>>>(valid, destb, X, V);   // final seq is in X
    heads_k<<<2048, 256, 0, stream>>>(V, pW, pb, cW, cb, PL, CL);

    crf_ll_k<9><<<32, 64, 0, stream>>>(PL, plab, nvm, p_start, p_end, p_trans, llb);
    crf_ll_k<3><<<32, 64, 0, stream>>>(CL, clab, nvm, c_start, c_end, c_trans, llb + 32);
    viterbi_k<9><<<32, 64, 0, stream>>>(PL, nvm, p_start, p_end, p_trans, out + 3);
    viterbi_k<3><<<32, 64, 0, stream>>>(CL, nvm, c_start, c_end, c_trans, out + 3 + 8192);
    finalize_k<<<1, 64, 0, stream>>>(llb, out);
}

// Round 3
// 11404.797 us; speedup vs baseline: 1.9809x; 1.7699x over previous
//
#include <hip/hip_runtime.h>
#include <cmath>

#define LSEQ 256
#define BB_ 32
#define DD_ 768
#define HH_ 384
#define M_ (BB_*LSEQ)        // 8192
#define G4H 1536

__device__ __forceinline__ float sigf(float x) { return 1.0f / (1.0f + expf(-x)); }

// coherent (L3 / agent-scope) scalar access helpers — compile to sc0 sc1, no fences
__device__ __forceinline__ float ld_coh(const float* p) {
    return __hip_atomic_load(p, __ATOMIC_RELAXED, __HIP_MEMORY_SCOPE_AGENT);
}
__device__ __forceinline__ void st_coh(float* p, float v) {
    __hip_atomic_store(p, v, __ATOMIC_RELAXED, __HIP_MEMORY_SCOPE_AGENT);
}
__device__ __forceinline__ unsigned ldu_coh(const unsigned* p) {
    return __hip_atomic_load(p, __ATOMIC_RELAXED, __HIP_MEMORY_SCOPE_AGENT);
}
__device__ __forceinline__ void stu_coh(unsigned* p, unsigned v) {
    __hip_atomic_store(p, v, __ATOMIC_RELAXED, __HIP_MEMORY_SCOPE_AGENT);
}

// ---------------------------------------------------------------- embed + LN
__global__ __launch_bounds__(256) void embed_ln_k(
    const int* __restrict__ ids, const int* __restrict__ tts,
    const float* __restrict__ wemb, const float* __restrict__ pemb,
    const float* __restrict__ temb, const float* __restrict__ lng,
    const float* __restrict__ lnb, float* __restrict__ X)
{
    const int blt = blockIdx.x;          // b*256 + l
    const int l = blt & 255;
    const int tid = threadIdx.x;
    const int id = ids[blt];
    const int tt = tts[blt];
    const size_t wb = (size_t)id * DD_;
    float e0 = wemb[wb + tid]       + pemb[l*DD_ + tid]       + temb[tt*DD_ + tid];
    float e1 = wemb[wb + tid + 256] + pemb[l*DD_ + tid + 256] + temb[tt*DD_ + tid + 256];
    float e2 = wemb[wb + tid + 512] + pemb[l*DD_ + tid + 512] + temb[tt*DD_ + tid + 512];
    __shared__ float red[256];
    red[tid] = e0 + e1 + e2;
    __syncthreads();
    for (int off = 128; off; off >>= 1) { if (tid < off) red[tid] += red[tid+off]; __syncthreads(); }
    const float mu = red[0] * (1.0f/768.0f);
    __syncthreads();
    const float d0 = e0-mu, d1 = e1-mu, d2 = e2-mu;
    red[tid] = d0*d0 + d1*d1 + d2*d2;
    __syncthreads();
    for (int off = 128; off; off >>= 1) { if (tid < off) red[tid] += red[tid+off]; __syncthreads(); }
    const float var = red[0] * (1.0f/768.0f);
    const float rs = 1.0f / sqrtf(var + 1e-12f);
    float* xo = X + (size_t)blt * DD_;
    xo[tid]     = d0*rs*lng[tid]     + lnb[tid];
    xo[tid+256] = d1*rs*lng[tid+256] + lnb[tid+256];
    xo[tid+512] = d2*rs*lng[tid+512] + lnb[tid+512];
}

// ------------------------------------------------- GEMM: G[d][m][n] = X@Wih^T + bias
__global__ __launch_bounds__(256) void gemm_xw_k(
    const float* __restrict__ X,    // [M][768]
    const float* __restrict__ Wih,  // [2][1536][768] (this layer)
    const float* __restrict__ b1,   // [2][1536]
    const float* __restrict__ b2,   // [2][1536]
    float* __restrict__ G)          // [2][M][1536]
{
    const int d  = blockIdx.z;
    const int m0 = blockIdx.x * 128;
    const int n0 = blockIdx.y * 64;
    const int tid = threadIdx.x;
    __shared__ float As[16][132];
    __shared__ float Bs[16][68];
    const int ty = tid >> 4;
    const int tx = tid & 15;
    float acc[8][4] = {};
    const float* Wd = Wih + (size_t)d * G4H * DD_;
    const int arow = tid >> 1, ahalf = tid & 1;
    const int brow = tid >> 2, bq = tid & 3;
    for (int k0 = 0; k0 < DD_; k0 += 16) {
        {
            const float* src = X + (size_t)(m0 + arow)*DD_ + k0 + ahalf*8;
            const float4 v0 = *(const float4*)src;
            const float4 v1 = *(const float4*)(src + 4);
            const int kk = ahalf*8;
            As[kk+0][arow]=v0.x; As[kk+1][arow]=v0.y; As[kk+2][arow]=v0.z; As[kk+3][arow]=v0.w;
            As[kk+4][arow]=v1.x; As[kk+5][arow]=v1.y; As[kk+6][arow]=v1.z; As[kk+7][arow]=v1.w;
        }
        {
            const float4 v = *(const float4*)(Wd + (size_t)(n0 + brow)*DD_ + k0 + bq*4);
            Bs[bq*4+0][brow]=v.x; Bs[bq*4+1][brow]=v.y; Bs[bq*4+2][brow]=v.z; Bs[bq*4+3][brow]=v.w;
        }
        __syncthreads();
        #pragma unroll
        for (int k = 0; k < 16; ++k) {
            const float4 a0 = *(const float4*)&As[k][ty*8];
            const float4 a1 = *(const float4*)&As[k][ty*8+4];
            const float4 bv = *(const float4*)&Bs[k][tx*4];
            const float ar[8] = {a0.x,a0.y,a0.z,a0.w,a1.x,a1.y,a1.z,a1.w};
            #pragma unroll
            for (int i = 0; i < 8; ++i) {
                acc[i][0] = fmaf(ar[i], bv.x, acc[i][0]);
                acc[i][1] = fmaf(ar[i], bv.y, acc[i][1]);
                acc[i][2] = fmaf(ar[i], bv.z, acc[i][2]);
                acc[i][3] = fmaf(ar[i], bv.w, acc[i][3]);
            }
        }
        __syncthreads();
    }
    const float* bb1 = b1 + d*G4H;
    const float* bb2 = b2 + d*G4H;
    #pragma unroll
    for (int i = 0; i < 8; ++i) {
        const int m = m0 + ty*8 + i;
        float* dst = G + ((size_t)d*M_ + m)*G4H + n0 + tx*4;
        #pragma unroll
        for (int j = 0; j < 4; ++j) {
            const int n = n0 + tx*4 + j;
            dst[j] = acc[i][j] + bb1[n] + bb2[n];
        }
    }
}

// ------------------------------------------------- LSTM recurrence (fence-free flags)
// grid 128: d = bid>>6, jb = bid&63 -> hidden units [jb*6, jb*6+6), 24 gate rows.
// Sync: per-block flag (own 128B line), relaxed sc0sc1 stores/loads via L3.
// h crosses blocks through relaxed agent-scope (write-through) accesses only.
__global__ __launch_bounds__(256) void recur_k(
    const float* __restrict__ G,    // [2][M][1536] pre-gates
    const float* __restrict__ Whh,  // [2][1536][384] (this layer)
    float* __restrict__ Yout,       // [B][L][768]
    float* __restrict__ H,          // [2 parity][2 dir][32][384]
    unsigned* __restrict__ flags)   // [2 dir][64 blocks][32 stride]
{
    const int bid = blockIdx.x;
    const int d  = bid >> 6;
    const int jb = bid & 63;
    const int j0 = jb * 6;
    const int tid = threadIdx.x;
    const int b  = tid >> 3;
    const int rr = tid & 7;
    unsigned* myflag = flags + ((size_t)d*64 + jb)*32;
    const unsigned* dirflags = flags + (size_t)d*64*32;

    __shared__ float w_s[24][388];
    __shared__ float gbuf[32][24];
    __shared__ float c_s[32*6];

    for (int idx = tid; idx < 24*384; idx += 256) {
        const int r = idx / 384, k = idx - r*384;
        const int n = (r/6)*384 + j0 + (r%6);
        w_s[r][k] = Whh[(size_t)d*G4H*HH_ + (size_t)n*HH_ + k];
    }
    if (tid < 192) c_s[tid] = 0.0f;
    __syncthreads();

    const int row0 = rr, row1 = rr+8, row2 = rr+16;
    const int n0 = (row0/6)*384 + j0 + (row0%6);
    const int n1 = (row1/6)*384 + j0 + (row1%6);
    const int n2 = (row2/6)*384 + j0 + (row2%6);

    // t = 0 pre-gates
    const int tt0 = d ? (LSEQ-1) : 0;
    size_t grow = ((size_t)d*M_ + (size_t)b*LSEQ + tt0) * G4H;
    float a0 = G[grow + n0];
    float a1 = G[grow + n1];
    float a2 = G[grow + n2];

    for (int t = 0; t < LSEQ; ++t) {
        if (t > 0) {
            // h of previous step: coherent scalar loads (L3), 8 lanes/b broadcast
            const float* hp = H + ((((size_t)((t-1)&1))*2 + d)*32 + b)*HH_;
            #pragma unroll 8
            for (int k4 = 0; k4 < 96; ++k4) {
                const int k = k4 << 2;
                const float h0 = ld_coh(hp+k+0);
                const float h1 = ld_coh(hp+k+1);
                const float h2 = ld_coh(hp+k+2);
                const float h3 = ld_coh(hp+k+3);
                const float4 w0 = *(const float4*)(&w_s[row0][k]);
                const float4 w1 = *(const float4*)(&w_s[row1][k]);
                const float4 w2 = *(const float4*)(&w_s[row2][k]);
                a0 = fmaf(h0,w0.x,fmaf(h1,w0.y,fmaf(h2,w0.z,fmaf(h3,w0.w,a0))));
                a1 = fmaf(h0,w1.x,fmaf(h1,w1.y,fmaf(h2,w1.z,fmaf(h3,w1.w,a1))));
                a2 = fmaf(h0,w2.x,fmaf(h1,w2.y,fmaf(h2,w2.z,fmaf(h3,w2.w,a2))));
            }
        }
        gbuf[b][row0] = a0; gbuf[b][row1] = a1; gbuf[b][row2] = a2;
        __syncthreads();

        // prefetch next step's pre-gates (independent of h)
        if (t + 1 < LSEQ) {
            const int ttn = d ? (LSEQ-2-t) : (t+1);
            grow = ((size_t)d*M_ + (size_t)b*LSEQ + ttn) * G4H;
            a0 = G[grow + n0];
            a1 = G[grow + n1];
            a2 = G[grow + n2];
        }

        if (tid < 192) {
            const int bb = tid / 6, jj = tid - bb*6;
            const float gi = gbuf[bb][jj];
            const float gf = gbuf[bb][6+jj];
            const float gg = gbuf[bb][12+jj];
            const float go = gbuf[bb][18+jj];
            const float c = sigf(gf)*c_s[tid] + sigf(gi)*tanhf(gg);
            const float h = sigf(go)*tanhf(c);
            c_s[tid] = c;
            // coherent (write-through) h publish
            st_coh(&H[((((size_t)(t&1))*2 + d)*32 + bb)*HH_ + j0 + jj], h);
            Yout[((size_t)bb*LSEQ + ((d ? (LSEQ-1-t) : t)))*DD_ + d*HH_ + j0 + jj] = h;
        }

        if (t + 1 < LSEQ) {
            asm volatile("s_waitcnt vmcnt(0)" ::: "memory");  // h stores at L3
            __syncthreads();                                   // whole block drained
            if (tid == 0) stu_coh(myflag, (unsigned)(t + 1));  // arrive (own line, no fence)
            if (tid < 64) {                                    // wave0: distributed wait
                const unsigned* fp = dirflags + tid*32;
                while (ldu_coh(fp) <= (unsigned)t) {
                    __builtin_amdgcn_s_sleep(1);
                }
            }
            __syncthreads();
        }
    }
}

// ------------------------------------------------- compaction scan
__global__ __launch_bounds__(256) void scan_k(
    const int* __restrict__ valid, const int* __restrict__ lmask,
    int* __restrict__ dest, int* __restrict__ nvm)
{
    const int b = blockIdx.x, l = threadIdx.x;
    __shared__ int arr[256];
    __shared__ int ms[256];
    arr[l] = valid[b*256 + l];
    ms[l]  = lmask[b*256 + l];
    __syncthreads();
    for (int off = 1; off < 256; off <<= 1) {
        const int add = arr[l] + ((l >= off) ? arr[l-off] : 0);
        __syncthreads();
        arr[l] = add;
        __syncthreads();
    }
    dest[b*256 + l] = arr[l] - 1;
    for (int off = 128; off; off >>= 1) { if (l < off) ms[l] += ms[l+off]; __syncthreads(); }
    if (l == 0) nvm[b] = ms[0];
}

__global__ __launch_bounds__(256) void scatter_k(
    const int* __restrict__ valid, const int* __restrict__ dest,
    const float* __restrict__ S, float* __restrict__ V)
{
    const int blt = blockIdx.x;
    if (!valid[blt]) return;
    const int b = blt >> 8;
    const int dd = dest[blt];
    const int tid = threadIdx.x;
    const float* src = S + (size_t)blt * DD_;
    float* dst = V + ((size_t)(b*256 + dd)) * DD_;
    dst[tid] = src[tid]; dst[tid+256] = src[tid+256]; dst[tid+512] = src[tid+512];
}

// ------------------------------------------------- heads: logits (wave per row)
__global__ __launch_bounds__(256) void heads_k(
    const float* __restrict__ V,
    const float* __restrict__ pW, const float* __restrict__ pb,
    const float* __restrict__ cW, const float* __restrict__ cb,
    float* __restrict__ PL, float* __restrict__ CL)
{
    const int w = threadIdx.x >> 6, lane = threadIdx.x & 63;
    const int m = blockIdx.x*4 + w;
    const float* vr = V + (size_t)m * DD_;
    float ap[9] = {}; float ac[3] = {};
    #pragma unroll
    for (int kk = 0; kk < 12; ++kk) {
        const int k = kk*64 + lane;
        const float v = vr[k];
        #pragma unroll
        for (int o = 0; o < 9; ++o) ap[o] = fmaf(v, pW[o*DD_ + k], ap[o]);
        #pragma unroll
        for (int o = 0; o < 3; ++o) ac[o] = fmaf(v, cW[o*DD_ + k], ac[o]);
    }
    #pragma unroll
    for (int o = 0; o < 9; ++o) {
        float r = ap[o];
        for (int off = 32; off; off >>= 1) r += __shfl_down(r, off);
        if (lane == 0) PL[(size_t)m*9 + o] = r + pb[o];
    }
    #pragma unroll
    for (int o = 0; o < 3; ++o) {
        float r = ac[o];
        for (int off = 32; off; off >>= 1) r += __shfl_down(r, off);
        if (lane == 0) CL[(size_t)m*3 + o] = r + cb[o];
    }
}

// ------------------------------------------------- CRF log-likelihood (wave per b)
template<int NT>
__global__ __launch_bounds__(64) void crf_ll_k(
    const float* __restrict__ E, const int* __restrict__ tg,
    const int* __restrict__ nvm,
    const float* __restrict__ st, const float* __restrict__ en,
    const float* __restrict__ tr, float* __restrict__ llout)
{
    const int b = blockIdx.x;
    const int lane = threadIdx.x;
    const int nv = nvm[b];
    const int base = b*256;
    float num = 0.0f;
    for (int t = lane; t < nv; t += 64) {
        const int tgt = tg[base + t];
        float c = E[(size_t)(base + t)*NT + tgt];
        if (t > 0) c += tr[tg[base + t - 1]*NT + tgt];
        num += c;
    }
    for (int off = 32; off; off >>= 1) num += __shfl_down(num, off);

    float trc[NT];
    float s;
    if (lane < NT) {
        #pragma unroll
        for (int i = 0; i < NT; ++i) trc[i] = tr[i*NT + lane];
        s = st[lane] + E[(size_t)base*NT + lane];
    } else {
        #pragma unroll
        for (int i = 0; i < NT; ++i) trc[i] = 0.0f;
        s = -INFINITY;
    }
    for (int t = 1; t < nv; ++t) {
        float si[NT];
        #pragma unroll
        for (int i = 0; i < NT; ++i) si[i] = __shfl(s, i) + trc[i];
        float m = si[0];
        #pragma unroll
        for (int i = 1; i < NT; ++i) m = fmaxf(m, si[i]);
        float sum = 0.0f;
        #pragma unroll
        for (int i = 0; i < NT; ++i) sum += expf(si[i] - m);
        if (lane < NT) s = m + logf(sum) + E[(size_t)(base + t)*NT + lane];
    }
    float v = (lane < NT) ? s + en[lane] : -INFINITY;
    float mx = v;
    for (int off = 32; off; off >>= 1) mx = fmaxf(mx, __shfl_xor(mx, off));
    float ex = (lane < NT) ? expf(v - mx) : 0.0f;
    for (int off = 32; off; off >>= 1) ex += __shfl_xor(ex, off);
    const float logZ = mx + logf(ex);
    if (lane == 0) {
        num += st[tg[base]] + en[tg[base + nv - 1]];
        llout[b] = num - logZ;
    }
}

// ------------------------------------------------- Viterbi decode (wave per b)
template<int NT>
__global__ __launch_bounds__(64) void viterbi_k(
    const float* __restrict__ E, const int* __restrict__ nvm,
    const float* __restrict__ st, const float* __restrict__ en,
    const float* __restrict__ tr, float* __restrict__ outp)
{
    const int b = blockIdx.x;
    const int lane = threadIdx.x;
    const int nv = nvm[b];
    const int base = b*256;
    float* o = outp + base;
    __shared__ unsigned char hist[256][16];
    float trc[NT];
    float s;
    if (lane < NT) {
        #pragma unroll
        for (int i = 0; i < NT; ++i) trc[i] = tr[i*NT + lane];
        s = st[lane] + E[(size_t)base*NT + lane];
    } else {
        #pragma unroll
        for (int i = 0; i < NT; ++i) trc[i] = 0.0f;
        s = -INFINITY;
    }
    for (int t = 1; t < nv; ++t) {
        float si[NT];
        #pragma unroll
        for (int i = 0; i < NT; ++i) si[i] = __shfl(s, i) + trc[i];
        float best = si[0];
        int bi = 0;
        #pragma unroll
        for (int i = 1; i < NT; ++i) if (si[i] > best) { best = si[i]; bi = i; }
        if (lane < NT) {
            hist[t][lane] = (unsigned char)bi;
            s = best + E[(size_t)(base + t)*NT + lane];
        }
    }
    float v = (lane < NT) ? s + en[lane] : -INFINITY;
    int idx = lane;
    for (int off = 32; off; off >>= 1) {
        const float ov = __shfl_xor(v, off);
        const int   oi = __shfl_xor(idx, off);
        if (ov > v || (ov == v && oi < idx)) { v = ov; idx = oi; }
    }
    __syncthreads();
    if (lane == 0) {
        int tag = idx;
        o[nv-1] = (float)tag;
        for (int t = nv - 1; t >= 1; --t) {
            tag = hist[t][tag];
            o[t-1] = (float)tag;
        }
    }
    for (int t = nv + lane; t < 256; t += 64) o[t] = 0.0f;
}

__global__ __launch_bounds__(64) void finalize_k(const float* __restrict__ llb,
                                                 float* __restrict__ out)
{
    const int lane = threadIdx.x;
    const float v = llb[lane];
    float p = (lane < 32) ? v : 0.0f;
    float c = (lane < 32) ? 0.0f : v;
    for (int off = 32; off; off >>= 1) { p += __shfl_down(p, off); c += __shfl_down(c, off); }
    if (lane == 0) { out[0] = -(p + c); out[1] = p; out[2] = c; }
}

// ================================================================ host
extern "C" void kernel_launch(void* const* d_in, const int* in_sizes, int n_in,
                              void* d_out, int out_size, void* d_ws, size_t ws_size,
                              hipStream_t stream) {
    const int*   input_ids = (const int*)d_in[0];
    const int*   tt_ids    = (const int*)d_in[1];
    const int*   valid     = (const int*)d_in[2];
    const int*   plab      = (const int*)d_in[3];
    const int*   clab      = (const int*)d_in[4];
    const int*   lmask     = (const int*)d_in[5];
    const float* wemb      = (const float*)d_in[6];
    const float* pemb      = (const float*)d_in[7];
    const float* temb      = (const float*)d_in[8];
    const float* ln_g      = (const float*)d_in[9];
    const float* ln_b      = (const float*)d_in[10];
    const float* Wih       = (const float*)d_in[11];
    const float* Whh       = (const float*)d_in[12];
    const float* bih       = (const float*)d_in[13];
    const float* bhh       = (const float*)d_in[14];
    const float* pW        = (const float*)d_in[15];
    const float* pb        = (const float*)d_in[16];
    const float* cW        = (const float*)d_in[17];
    const float* cb        = (const float*)d_in[18];
    const float* p_start   = (const float*)d_in[19];
    const float* p_end     = (const float*)d_in[20];
    const float* p_trans   = (const float*)d_in[21];
    const float* c_start   = (const float*)d_in[22];
    const float* c_end     = (const float*)d_in[23];
    const float* c_trans   = (const float*)d_in[24];

    float* ws = (float*)d_ws;
    float* X   = ws;                       // 6,291,456
    float* Y   = X  + 6291456;             // 6,291,456
    float* Gb  = Y  + 6291456;             // 25,165,824
    float* V   = Gb + 25165824;            // 6,291,456
    float* PL  = V  + 6291456;             // 73,728
    float* CL  = PL + 73728;               // 24,576
    float* Hb  = CL + 24576;               // 98,304
    float* llb = Hb + 98304;               // 64
    int*   destb = (int*)(llb + 64);       // 8192 ints
    int*   nvm   = destb + 8192;           // 32 ints
    unsigned* flags = (unsigned*)(nvm + 32); // [2 layer][2 dir][64][32] = 16384 u32
    float* out = (float*)d_out;

    embed_ln_k<<<8192, 256, 0, stream>>>(input_ids, tt_ids, wemb, pemb, temb, ln_g, ln_b, X);
    hipMemsetAsync(flags, 0, 16384 * sizeof(unsigned), stream);

    for (int layer = 0; layer < 2; ++layer) {
        const float* Xin  = layer ? Y : X;
        float*       Yout = layer ? X : Y;
        const float* Wl  = Wih + (size_t)layer * 2 * G4H * DD_;
        const float* Whl = Whh + (size_t)layer * 2 * G4H * HH_;
        const float* b1  = bih + (size_t)layer * 2 * G4H;
        const float* b2  = bhh + (size_t)layer * 2 * G4H;
        gemm_xw_k<<<dim3(64, 24, 2), 256, 0, stream>>>(Xin, Wl, b1, b2, Gb);
        const float* gA = Gb; const float* wA = Whl; float* yA = Yout; float* hA = Hb;
        unsigned* flA = flags + (size_t)layer * 2 * 64 * 32;
        void* kargs[] = { (void*)&gA, (void*)&wA, (void*)&yA, (void*)&hA, (void*)&flA };
        hipLaunchCooperativeKernel((const void*)recur_k, dim3(128), dim3(256), kargs, 0, stream);
    }

    scan_k<<<32, 256, 0, stream>>>(valid, lmask, destb, nvm);
    hipMemsetAsync(V, 0, (size_t)6291456 * 4, stream);
    scatter_k<<<8192, 256, 0, stream>>>(valid, destb, X, V);   // final seq is in X
    heads_k<<<2048, 256, 0, stream>>>(V, pW, pb, cW, cb, PL, CL);

    crf_ll_k<9><<<32, 64, 0, stream>>>(PL, plab, nvm, p_start, p_end, p_trans, llb);
    crf_ll_k<3><<<32, 64, 0, stream>>>(CL, clab, nvm, c_start, c_end, c_trans, llb + 32);
    viterbi_k<9><<<32, 64, 0, stream>>>(PL, nvm, p_start, p_end, p_trans, out + 3);
    viterbi_k<3><<<32, 64, 0, stream>>>(CL, nvm, c_start, c_end, c_trans, out + 3 + 8192);
    finalize_k<<<1, 64, 0, stream>>>(llb, out);
}

// Round 5
// 9007.548 us; speedup vs baseline: 2.5081x; 1.2661x over previous
//
#include <hip/hip_runtime.h>
#include <cmath>

#define LSEQ 256
#define BB_ 32
#define DD_ 768
#define HH_ 384
#define M_ (BB_*LSEQ)        // 8192
#define G4H 1536

__device__ __forceinline__ float sigf(float x) { return 1.0f / (1.0f + expf(-x)); }

// coherent (L3 / agent-scope) scalar access helpers — compile to sc0 sc1, no fences
__device__ __forceinline__ float ld_coh(const float* p) {
    return __hip_atomic_load(p, __ATOMIC_RELAXED, __HIP_MEMORY_SCOPE_AGENT);
}
__device__ __forceinline__ void st_coh(float* p, float v) {
    __hip_atomic_store(p, v, __ATOMIC_RELAXED, __HIP_MEMORY_SCOPE_AGENT);
}
__device__ __forceinline__ unsigned ldu_coh(const unsigned* p) {
    return __hip_atomic_load(p, __ATOMIC_RELAXED, __HIP_MEMORY_SCOPE_AGENT);
}
__device__ __forceinline__ void stu_coh(unsigned* p, unsigned v) {
    __hip_atomic_store(p, v, __ATOMIC_RELAXED, __HIP_MEMORY_SCOPE_AGENT);
}

// ---------------------------------------------------------------- embed + LN
__global__ __launch_bounds__(256) void embed_ln_k(
    const int* __restrict__ ids, const int* __restrict__ tts,
    const float* __restrict__ wemb, const float* __restrict__ pemb,
    const float* __restrict__ temb, const float* __restrict__ lng,
    const float* __restrict__ lnb, float* __restrict__ X)
{
    const int blt = blockIdx.x;          // b*256 + l
    const int l = blt & 255;
    const int tid = threadIdx.x;
    const int id = ids[blt];
    const int tt = tts[blt];
    const size_t wb = (size_t)id * DD_;
    float e0 = wemb[wb + tid]       + pemb[l*DD_ + tid]       + temb[tt*DD_ + tid];
    float e1 = wemb[wb + tid + 256] + pemb[l*DD_ + tid + 256] + temb[tt*DD_ + tid + 256];
    float e2 = wemb[wb + tid + 512] + pemb[l*DD_ + tid + 512] + temb[tt*DD_ + tid + 512];
    __shared__ float red[256];
    red[tid] = e0 + e1 + e2;
    __syncthreads();
    for (int off = 128; off; off >>= 1) { if (tid < off) red[tid] += red[tid+off]; __syncthreads(); }
    const float mu = red[0] * (1.0f/768.0f);
    __syncthreads();
    const float d0 = e0-mu, d1 = e1-mu, d2 = e2-mu;
    red[tid] = d0*d0 + d1*d1 + d2*d2;
    __syncthreads();
    for (int off = 128; off; off >>= 1) { if (tid < off) red[tid] += red[tid+off]; __syncthreads(); }
    const float var = red[0] * (1.0f/768.0f);
    const float rs = 1.0f / sqrtf(var + 1e-12f);
    float* xo = X + (size_t)blt * DD_;
    xo[tid]     = d0*rs*lng[tid]     + lnb[tid];
    xo[tid+256] = d1*rs*lng[tid+256] + lnb[tid+256];
    xo[tid+512] = d2*rs*lng[tid+512] + lnb[tid+512];
}

// ------------------------------------------------- GEMM: G[d][m][n] = X@Wih^T + bias
__global__ __launch_bounds__(256) void gemm_xw_k(
    const float* __restrict__ X,    // [M][768]
    const float* __restrict__ Wih,  // [2][1536][768] (this layer)
    const float* __restrict__ b1,   // [2][1536]
    const float* __restrict__ b2,   // [2][1536]
    float* __restrict__ G)          // [2][M][1536]
{
    const int d  = blockIdx.z;
    const int m0 = blockIdx.x * 128;
    const int n0 = blockIdx.y * 64;
    const int tid = threadIdx.x;
    __shared__ float As[16][132];
    __shared__ float Bs[16][68];
    const int ty = tid >> 4;
    const int tx = tid & 15;
    float acc[8][4] = {};
    const float* Wd = Wih + (size_t)d * G4H * DD_;
    const int arow = tid >> 1, ahalf = tid & 1;
    const int brow = tid >> 2, bq = tid & 3;
    for (int k0 = 0; k0 < DD_; k0 += 16) {
        {
            const float* src = X + (size_t)(m0 + arow)*DD_ + k0 + ahalf*8;
            const float4 v0 = *(const float4*)src;
            const float4 v1 = *(const float4*)(src + 4);
            const int kk = ahalf*8;
            As[kk+0][arow]=v0.x; As[kk+1][arow]=v0.y; As[kk+2][arow]=v0.z; As[kk+3][arow]=v0.w;
            As[kk+4][arow]=v1.x; As[kk+5][arow]=v1.y; As[kk+6][arow]=v1.z; As[kk+7][arow]=v1.w;
        }
        {
            const float4 v = *(const float4*)(Wd + (size_t)(n0 + brow)*DD_ + k0 + bq*4);
            Bs[bq*4+0][brow]=v.x; Bs[bq*4+1][brow]=v.y; Bs[bq*4+2][brow]=v.z; Bs[bq*4+3][brow]=v.w;
        }
        __syncthreads();
        #pragma unroll
        for (int k = 0; k < 16; ++k) {
            const float4 a0 = *(const float4*)&As[k][ty*8];
            const float4 a1 = *(const float4*)&As[k][ty*8+4];
            const float4 bv = *(const float4*)&Bs[k][tx*4];
            const float ar[8] = {a0.x,a0.y,a0.z,a0.w,a1.x,a1.y,a1.z,a1.w};
            #pragma unroll
            for (int i = 0; i < 8; ++i) {
                acc[i][0] = fmaf(ar[i], bv.x, acc[i][0]);
                acc[i][1] = fmaf(ar[i], bv.y, acc[i][1]);
                acc[i][2] = fmaf(ar[i], bv.z, acc[i][2]);
                acc[i][3] = fmaf(ar[i], bv.w, acc[i][3]);
            }
        }
        __syncthreads();
    }
    const float* bb1 = b1 + d*G4H;
    const float* bb2 = b2 + d*G4H;
    #pragma unroll
    for (int i = 0; i < 8; ++i) {
        const int m = m0 + ty*8 + i;
        float* dst = G + ((size_t)d*M_ + m)*G4H + n0 + tx*4;
        #pragma unroll
        for (int j = 0; j < 4; ++j) {
            const int n = n0 + tx*4 + j;
            dst[j] = acc[i][j] + bb1[n] + bb2[n];
        }
    }
}

// ------------------------------------------------- LSTM recurrence (LDS-staged h, flag sync)
// grid 128: d = bid>>6, jb = bid&63 -> hidden units [jb*6, jb*6+6), 24 gate rows.
// Round-3 structure; single delta: h is staged into LDS (48 coherent loads per
// thread instead of 384), then the dot loop reads h from LDS (broadcast reads).
__global__ __launch_bounds__(256) void recur_k(
    const float* __restrict__ G,    // [2][M][1536] pre-gates
    const float* __restrict__ Whh,  // [2][1536][384] (this layer)
    float* __restrict__ Yout,       // [B][L][768]
    float* __restrict__ H,          // [2 parity][2 dir][32][384]
    unsigned* __restrict__ flags)   // [2 dir][64 blocks][32 stride]
{
    const int bid = blockIdx.x;
    const int d  = bid >> 6;
    const int jb = bid & 63;
    const int j0 = jb * 6;
    const int tid = threadIdx.x;
    const int b  = tid >> 3;
    const int rr = tid & 7;
    unsigned* myflag = flags + ((size_t)d*64 + jb)*32;
    const unsigned* dirflags = flags + (size_t)d*64*32;

    __shared__ float w_s[24][388];
    __shared__ float hs[32][388];
    __shared__ float gbuf[32][24];
    __shared__ float c_s[32*6];

    for (int idx = tid; idx < 24*384; idx += 256) {
        const int r = idx / 384, k = idx - r*384;
        const int n = (r/6)*384 + j0 + (r%6);
        w_s[r][k] = Whh[(size_t)d*G4H*HH_ + (size_t)n*HH_ + k];
    }
    if (tid < 192) c_s[tid] = 0.0f;
    __syncthreads();

    const int row0 = rr, row1 = rr+8, row2 = rr+16;
    const int n0 = (row0/6)*384 + j0 + (row0%6);
    const int n1 = (row1/6)*384 + j0 + (row1%6);
    const int n2 = (row2/6)*384 + j0 + (row2%6);

    // t = 0 pre-gates
    const int tt0 = d ? (LSEQ-1) : 0;
    size_t grow = ((size_t)d*M_ + (size_t)b*LSEQ + tt0) * G4H;
    float a0 = G[grow + n0];
    float a1 = G[grow + n1];
    float a2 = G[grow + n2];

    for (int t = 0; t < LSEQ; ++t) {
        if (t > 0) {
            // stage prev h into LDS: thread (b,rr) loads its 48-float slice (coherent)
            {
                const float* hp = H + ((((size_t)((t-1)&1))*2 + d)*32 + b)*HH_ + rr*48;
                float* hd = &hs[b][rr*48];
                #pragma unroll
                for (int i = 0; i < 48; i += 4) {
                    const float v0 = ld_coh(hp + i + 0);
                    const float v1 = ld_coh(hp + i + 1);
                    const float v2 = ld_coh(hp + i + 2);
                    const float v3 = ld_coh(hp + i + 3);
                    hd[i+0] = v0; hd[i+1] = v1; hd[i+2] = v2; hd[i+3] = v3;
                }
            }
            __syncthreads();   // uniform branch: all threads reach this
            const float* hb = hs[b];
            #pragma unroll 8
            for (int k4 = 0; k4 < 96; ++k4) {
                const float4 h4 = *(const float4*)(hb + (k4<<2));
                const float4 w0 = *(const float4*)(&w_s[row0][k4<<2]);
                const float4 w1 = *(const float4*)(&w_s[row1][k4<<2]);
                const float4 w2 = *(const float4*)(&w_s[row2][k4<<2]);
                a0 = fmaf(h4.x,w0.x,fmaf(h4.y,w0.y,fmaf(h4.z,w0.z,fmaf(h4.w,w0.w,a0))));
                a1 = fmaf(h4.x,w1.x,fmaf(h4.y,w1.y,fmaf(h4.z,w1.z,fmaf(h4.w,w1.w,a1))));
                a2 = fmaf(h4.x,w2.x,fmaf(h4.y,w2.y,fmaf(h4.z,w2.z,fmaf(h4.w,w2.w,a2))));
            }
        }
        gbuf[b][row0] = a0; gbuf[b][row1] = a1; gbuf[b][row2] = a2;
        __syncthreads();

        // prefetch next step's pre-gates (independent of h)
        if (t + 1 < LSEQ) {
            const int ttn = d ? (LSEQ-2-t) : (t+1);
            grow = ((size_t)d*M_ + (size_t)b*LSEQ + ttn) * G4H;
            a0 = G[grow + n0];
            a1 = G[grow + n1];
            a2 = G[grow + n2];
        }

        if (tid < 192) {
            const int bb = tid / 6, jj = tid - bb*6;
            const float gi = gbuf[bb][jj];
            const float gf = gbuf[bb][6+jj];
            const float gg = gbuf[bb][12+jj];
            const float go = gbuf[bb][18+jj];
            const float c = sigf(gf)*c_s[tid] + sigf(gi)*tanhf(gg);
            const float h = sigf(go)*tanhf(c);
            c_s[tid] = c;
            // coherent (write-through) h publish
            st_coh(&H[((((size_t)(t&1))*2 + d)*32 + bb)*HH_ + j0 + jj], h);
            Yout[((size_t)bb*LSEQ + ((d ? (LSEQ-1-t) : t)))*DD_ + d*HH_ + j0 + jj] = h;
        }

        if (t + 1 < LSEQ) {
            asm volatile("s_waitcnt vmcnt(0)" ::: "memory");  // h stores at L3
            __syncthreads();                                   // whole block drained
            if (tid == 0) stu_coh(myflag, (unsigned)(t + 1));  // arrive (own line)
            if (tid < 64) {                                    // wave0: distributed wait
                const unsigned* fp = dirflags + tid*32;
                while (ldu_coh(fp) <= (unsigned)t) {
                    __builtin_amdgcn_s_sleep(1);
                }
            }
            __syncthreads();
        }
    }
}

// ------------------------------------------------- compaction scan
__global__ __launch_bounds__(256) void scan_k(
    const int* __restrict__ valid, const int* __restrict__ lmask,
    int* __restrict__ dest, int* __restrict__ nvm)
{
    const int b = blockIdx.x, l = threadIdx.x;
    __shared__ int arr[256];
    __shared__ int ms[256];
    arr[l] = valid[b*256 + l];
    ms[l]  = lmask[b*256 + l];
    __syncthreads();
    for (int off = 1; off < 256; off <<= 1) {
        const int add = arr[l] + ((l >= off) ? arr[l-off] : 0);
        __syncthreads();
        arr[l] = add;
        __syncthreads();
    }
    dest[b*256 + l] = arr[l] - 1;
    for (int off = 128; off; off >>= 1) { if (l < off) ms[l] += ms[l+off]; __syncthreads(); }
    if (l == 0) nvm[b] = ms[0];
}

__global__ __launch_bounds__(256) void scatter_k(
    const int* __restrict__ valid, const int* __restrict__ dest,
    const float* __restrict__ S, float* __restrict__ V)
{
    const int blt = blockIdx.x;
    if (!valid[blt]) return;
    const int b = blt >> 8;
    const int dd = dest[blt];
    const int tid = threadIdx.x;
    const float* src = S + (size_t)blt * DD_;
    float* dst = V + ((size_t)(b*256 + dd)) * DD_;
    dst[tid] = src[tid]; dst[tid+256] = src[tid+256]; dst[tid+512] = src[tid+512];
}

// ------------------------------------------------- heads: logits (wave per row)
__global__ __launch_bounds__(256) void heads_k(
    const float* __restrict__ V,
    const float* __restrict__ pW, const float* __restrict__ pb,
    const float* __restrict__ cW, const float* __restrict__ cb,
    float* __restrict__ PL, float* __restrict__ CL)
{
    const int w = threadIdx.x >> 6, lane = threadIdx.x & 63;
    const int m = blockIdx.x*4 + w;
    const float* vr = V + (size_t)m * DD_;
    float ap[9] = {}; float ac[3] = {};
    #pragma unroll
    for (int kk = 0; kk < 12; ++kk) {
        const int k = kk*64 + lane;
        const float v = vr[k];
        #pragma unroll
        for (int o = 0; o < 9; ++o) ap[o] = fmaf(v, pW[o*DD_ + k], ap[o]);
        #pragma unroll
        for (int o = 0; o < 3; ++o) ac[o] = fmaf(v, cW[o*DD_ + k], ac[o]);
    }
    #pragma unroll
    for (int o = 0; o < 9; ++o) {
        float r = ap[o];
        for (int off = 32; off; off >>= 1) r += __shfl_down(r, off);
        if (lane == 0) PL[(size_t)m*9 + o] = r + pb[o];
    }
    #pragma unroll
    for (int o = 0; o < 3; ++o) {
        float r = ac[o];
        for (int off = 32; off; off >>= 1) r += __shfl_down(r, off);
        if (lane == 0) CL[(size_t)m*3 + o] = r + cb[o];
    }
}

// ------------------------------------------------- CRF log-likelihood (wave per b)
template<int NT>
__global__ __launch_bounds__(64) void crf_ll_k(
    const float* __restrict__ E, const int* __restrict__ tg,
    const int* __restrict__ nvm,
    const float* __restrict__ st, const float* __restrict__ en,
    const float* __restrict__ tr, float* __restrict__ llout)
{
    const int b = blockIdx.x;
    const int lane = threadIdx.x;
    const int nv = nvm[b];
    const int base = b*256;
    float num = 0.0f;
    for (int t = lane; t < nv; t += 64) {
        const int tgt = tg[base + t];
        float c = E[(size_t)(base + t)*NT + tgt];
        if (t > 0) c += tr[tg[base + t - 1]*NT + tgt];
        num += c;
    }
    for (int off = 32; off; off >>= 1) num += __shfl_down(num, off);

    float trc[NT];
    float s;
    if (lane < NT) {
        #pragma unroll
        for (int i = 0; i < NT; ++i) trc[i] = tr[i*NT + lane];
        s = st[lane] + E[(size_t)base*NT + lane];
    } else {
        #pragma unroll
        for (int i = 0; i < NT; ++i) trc[i] = 0.0f;
        s = -INFINITY;
    }
    for (int t = 1; t < nv; ++t) {
        float si[NT];
        #pragma unroll
        for (int i = 0; i < NT; ++i) si[i] = __shfl(s, i) + trc[i];
        float m = si[0];
        #pragma unroll
        for (int i = 1; i < NT; ++i) m = fmaxf(m, si[i]);
        float sum = 0.0f;
        #pragma unroll
        for (int i = 0; i < NT; ++i) sum += expf(si[i] - m);
        if (lane < NT) s = m + logf(sum) + E[(size_t)(base + t)*NT + lane];
    }
    float v = (lane < NT) ? s + en[lane] : -INFINITY;
    float mx = v;
    for (int off = 32; off; off >>= 1) mx = fmaxf(mx, __shfl_xor(mx, off));
    float ex = (lane < NT) ? expf(v - mx) : 0.0f;
    for (int off = 32; off; off >>= 1) ex += __shfl_xor(ex, off);
    const float logZ = mx + logf(ex);
    if (lane == 0) {
        num += st[tg[base]] + en[tg[base + nv - 1]];
        llout[b] = num - logZ;
    }
}

// ------------------------------------------------- Viterbi decode (wave per b)
template<int NT>
__global__ __launch_bounds__(64) void viterbi_k(
    const float* __restrict__ E, const int* __restrict__ nvm,
    const float* __restrict__ st, const float* __restrict__ en,
    const float* __restrict__ tr, float* __restrict__ outp)
{
    const int b = blockIdx.x;
    const int lane = threadIdx.x;
    const int nv = nvm[b];
    const int base = b*256;
    float* o = outp + base;
    __shared__ unsigned char hist[256][16];
    float trc[NT];
    float s;
    if (lane < NT) {
        #pragma unroll
        for (int i = 0; i < NT; ++i) trc[i] = tr[i*NT + lane];
        s = st[lane] + E[(size_t)base*NT + lane];
    } else {
        #pragma unroll
        for (int i = 0; i < NT; ++i) trc[i] = 0.0f;
        s = -INFINITY;
    }
    for (int t = 1; t < nv; ++t) {
        float si[NT];
        #pragma unroll
        for (int i = 0; i < NT; ++i) si[i] = __shfl(s, i) + trc[i];
        float best = si[0];
        int bi = 0;
        #pragma unroll
        for (int i = 1; i < NT; ++i) if (si[i] > best) { best = si[i]; bi = i; }
        if (lane < NT) {
            hist[t][lane] = (unsigned char)bi;
            s = best + E[(size_t)(base + t)*NT + lane];
        }
    }
    float v = (lane < NT) ? s + en[lane] : -INFINITY;
    int idx = lane;
    for (int off = 32; off; off >>= 1) {
        const float ov = __shfl_xor(v, off);
        const int   oi = __shfl_xor(idx, off);
        if (ov > v || (ov == v && oi < idx)) { v = ov; idx = oi; }
    }
    __syncthreads();
    if (lane == 0) {
        int tag = idx;
        o[nv-1] = (float)tag;
        for (int t = nv - 1; t >= 1; --t) {
            tag = hist[t][tag];
            o[t-1] = (float)tag;
        }
    }
    for (int t = nv + lane; t < 256; t += 64) o[t] = 0.0f;
}

__global__ __launch_bounds__(64) void finalize_k(const float* __restrict__ llb,
                                                 float* __restrict__ out)
{
    const int lane = threadIdx.x;
    const float v = llb[lane];
    float p = (lane < 32) ? v : 0.0f;
    float c = (lane < 32) ? 0.0f : v;
    for (int off = 32; off; off >>= 1) { p += __shfl_down(p, off); c += __shfl_down(c, off); }
    if (lane == 0) { out[0] = -(p + c); out[1] = p; out[2] = c; }
}

// ================================================================ host
extern "C" void kernel_launch(void* const* d_in, const int* in_sizes, int n_in,
                              void* d_out, int out_size, void* d_ws, size_t ws_size,
                              hipStream_t stream) {
    const int*   input_ids = (const int*)d_in[0];
    const int*   tt_ids    = (const int*)d_in[1];
    const int*   valid     = (const int*)d_in[2];
    const int*   plab      = (const int*)d_in[3];
    const int*   clab      = (const int*)d_in[4];
    const int*   lmask     = (const int*)d_in[5];
    const float* wemb      = (const float*)d_in[6];
    const float* pemb      = (const float*)d_in[7];
    const float* temb      = (const float*)d_in[8];
    const float* ln_g      = (const float*)d_in[9];
    const float* ln_b      = (const float*)d_in[10];
    const float* Wih       = (const float*)d_in[11];
    const float* Whh       = (const float*)d_in[12];
    const float* bih       = (const float*)d_in[13];
    const float* bhh       = (const float*)d_in[14];
    const float* pW        = (const float*)d_in[15];
    const float* pb        = (const float*)d_in[16];
    const float* cW        = (const float*)d_in[17];
    const float* cb        = (const float*)d_in[18];
    const float* p_start   = (const float*)d_in[19];
    const float* p_end     = (const float*)d_in[20];
    const float* p_trans   = (const float*)d_in[21];
    const float* c_start   = (const float*)d_in[22];
    const float* c_end     = (const float*)d_in[23];
    const float* c_trans   = (const float*)d_in[24];

    float* ws = (float*)d_ws;
    float* X   = ws;                       // 6,291,456
    float* Y   = X  + 6291456;             // 6,291,456
    float* Gb  = Y  + 6291456;             // 25,165,824
    float* V   = Gb + 25165824;            // 6,291,456
    float* PL  = V  + 6291456;             // 73,728
    float* CL  = PL + 73728;               // 24,576
    float* Hb  = CL + 24576;               // 98,304
    float* llb = Hb + 98304;               // 64
    int*   destb = (int*)(llb + 64);       // 8192 ints
    int*   nvm   = destb + 8192;           // 32 ints
    unsigned* flags = (unsigned*)(nvm + 32); // [2 layer][2 dir][64][32] u32
    float* out = (float*)d_out;

    embed_ln_k<<<8192, 256, 0, stream>>>(input_ids, tt_ids, wemb, pemb, temb, ln_g, ln_b, X);
    hipMemsetAsync(flags, 0, 16384 * sizeof(unsigned), stream);

    for (int layer = 0; layer < 2; ++layer) {
        const float* Xin  = layer ? Y : X;
        float*       Yout = layer ? X : Y;
        const float* Wl  = Wih + (size_t)layer * 2 * G4H * DD_;
        const float* Whl = Whh + (size_t)layer * 2 * G4H * HH_;
        const float* b1  = bih + (size_t)layer * 2 * G4H;
        const float* b2  = bhh + (size_t)layer * 2 * G4H;
        gemm_xw_k<<<dim3(64, 24, 2), 256, 0, stream>>>(Xin, Wl, b1, b2, Gb);
        const float* gA = Gb; const float* wA = Whl; float* yA = Yout; float* hA = Hb;
        unsigned* flA = flags + (size_t)layer * 2 * 64 * 32;
        void* kargs[] = { (void*)&gA, (void*)&wA, (void*)&yA, (void*)&hA, (void*)&flA };
        hipLaunchCooperativeKernel((const void*)recur_k, dim3(128), dim3(256), kargs, 0, stream);
    }

    scan_k<<<32, 256, 0, stream>>>(valid, lmask, destb, nvm);
    hipMemsetAsync(V, 0, (size_t)6291456 * 4, stream);
    scatter_k<<<8192, 256, 0, stream>>>(valid, destb, X, V);   // final seq is in X
    heads_k<<<2048, 256, 0, stream>>>(V, pW, pb, cW, cb, PL, CL);

    crf_ll_k<9><<<32, 64, 0, stream>>>(PL, plab, nvm, p_start, p_end, p_trans, llb);
    crf_ll_k<3><<<32, 64, 0, stream>>>(CL, clab, nvm, c_start, c_end, c_trans, llb + 32);
    viterbi_k<9><<<32, 64, 0, stream>>>(PL, nvm, p_start, p_end, p_trans, out + 3);
    viterbi_k<3><<<32, 64, 0, stream>>>(CL, nvm, c_start, c_end, c_trans, out + 3 + 8192);
    finalize_k<<<1, 64, 0, stream>>>(llb, out);
}

// Round 7
// 5258.081 us; speedup vs baseline: 4.2966x; 1.7131x over previous
//
#include <hip/hip_runtime.h>
#include <cmath>

#define LSEQ 256
#define BB_ 32
#define DD_ 768
#define HH_ 384
#define M_ (BB_*LSEQ)        // 8192
#define G4H 1536

__device__ __forceinline__ float sigf(float x) { return 1.0f / (1.0f + expf(-x)); }

// coherent (L3 / agent-scope) scalar access helpers — compile to sc0 sc1, no fences
__device__ __forceinline__ float ld_coh(const float* p) {
    return __hip_atomic_load(p, __ATOMIC_RELAXED, __HIP_MEMORY_SCOPE_AGENT);
}
__device__ __forceinline__ void st_coh(float* p, float v) {
    __hip_atomic_store(p, v, __ATOMIC_RELAXED, __HIP_MEMORY_SCOPE_AGENT);
}
__device__ __forceinline__ unsigned ldu_coh(const unsigned* p) {
    return __hip_atomic_load(p, __ATOMIC_RELAXED, __HIP_MEMORY_SCOPE_AGENT);
}
__device__ __forceinline__ void stu_coh(unsigned* p, unsigned v) {
    __hip_atomic_store(p, v, __ATOMIC_RELAXED, __HIP_MEMORY_SCOPE_AGENT);
}

// ---------------------------------------------------------------- embed + LN
__global__ __launch_bounds__(256) void embed_ln_k(
    const int* __restrict__ ids, const int* __restrict__ tts,
    const float* __restrict__ wemb, const float* __restrict__ pemb,
    const float* __restrict__ temb, const float* __restrict__ lng,
    const float* __restrict__ lnb, float* __restrict__ X)
{
    const int blt = blockIdx.x;          // b*256 + l
    const int l = blt & 255;
    const int tid = threadIdx.x;
    const int id = ids[blt];
    const int tt = tts[blt];
    const size_t wb = (size_t)id * DD_;
    float e0 = wemb[wb + tid]       + pemb[l*DD_ + tid]       + temb[tt*DD_ + tid];
    float e1 = wemb[wb + tid + 256] + pemb[l*DD_ + tid + 256] + temb[tt*DD_ + tid + 256];
    float e2 = wemb[wb + tid + 512] + pemb[l*DD_ + tid + 512] + temb[tt*DD_ + tid + 512];
    __shared__ float red[256];
    red[tid] = e0 + e1 + e2;
    __syncthreads();
    for (int off = 128; off; off >>= 1) { if (tid < off) red[tid] += red[tid+off]; __syncthreads(); }
    const float mu = red[0] * (1.0f/768.0f);
    __syncthreads();
    const float d0 = e0-mu, d1 = e1-mu, d2 = e2-mu;
    red[tid] = d0*d0 + d1*d1 + d2*d2;
    __syncthreads();
    for (int off = 128; off; off >>= 1) { if (tid < off) red[tid] += red[tid+off]; __syncthreads(); }
    const float var = red[0] * (1.0f/768.0f);
    const float rs = 1.0f / sqrtf(var + 1e-12f);
    float* xo = X + (size_t)blt * DD_;
    xo[tid]     = d0*rs*lng[tid]     + lnb[tid];
    xo[tid+256] = d1*rs*lng[tid+256] + lnb[tid+256];
    xo[tid+512] = d2*rs*lng[tid+512] + lnb[tid+512];
}

// ------------------------------------------------- GEMM: G[d][m][n] = X@Wih^T + bias
__global__ __launch_bounds__(256) void gemm_xw_k(
    const float* __restrict__ X,    // [M][768]
    const float* __restrict__ Wih,  // [2][1536][768] (this layer)
    const float* __restrict__ b1,   // [2][1536]
    const float* __restrict__ b2,   // [2][1536]
    float* __restrict__ G)          // [2][M][1536]
{
    const int d  = blockIdx.z;
    const int m0 = blockIdx.x * 128;
    const int n0 = blockIdx.y * 64;
    const int tid = threadIdx.x;
    __shared__ float As[16][132];
    __shared__ float Bs[16][68];
    const int ty = tid >> 4;
    const int tx = tid & 15;
    float acc[8][4] = {};
    const float* Wd = Wih + (size_t)d * G4H * DD_;
    const int arow = tid >> 1, ahalf = tid & 1;
    const int brow = tid >> 2, bq = tid & 3;
    for (int k0 = 0; k0 < DD_; k0 += 16) {
        {
            const float* src = X + (size_t)(m0 + arow)*DD_ + k0 + ahalf*8;
            const float4 v0 = *(const float4*)src;
            const float4 v1 = *(const float4*)(src + 4);
            const int kk = ahalf*8;
            As[kk+0][arow]=v0.x; As[kk+1][arow]=v0.y; As[kk+2][arow]=v0.z; As[kk+3][arow]=v0.w;
            As[kk+4][arow]=v1.x; As[kk+5][arow]=v1.y; As[kk+6][arow]=v1.z; As[kk+7][arow]=v1.w;
        }
        {
            const float4 v = *(const float4*)(Wd + (size_t)(n0 + brow)*DD_ + k0 + bq*4);
            Bs[bq*4+0][brow]=v.x; Bs[bq*4+1][brow]=v.y; Bs[bq*4+2][brow]=v.z; Bs[bq*4+3][brow]=v.w;
        }
        __syncthreads();
        #pragma unroll
        for (int k = 0; k < 16; ++k) {
            const float4 a0 = *(const float4*)&As[k][ty*8];
            const float4 a1 = *(const float4*)&As[k][ty*8+4];
            const float4 bv = *(const float4*)&Bs[k][tx*4];
            const float ar[8] = {a0.x,a0.y,a0.z,a0.w,a1.x,a1.y,a1.z,a1.w};
            #pragma unroll
            for (int i = 0; i < 8; ++i) {
                acc[i][0] = fmaf(ar[i], bv.x, acc[i][0]);
                acc[i][1] = fmaf(ar[i], bv.y, acc[i][1]);
                acc[i][2] = fmaf(ar[i], bv.z, acc[i][2]);
                acc[i][3] = fmaf(ar[i], bv.w, acc[i][3]);
            }
        }
        __syncthreads();
    }
    const float* bb1 = b1 + d*G4H;
    const float* bb2 = b2 + d*G4H;
    #pragma unroll
    for (int i = 0; i < 8; ++i) {
        const int m = m0 + ty*8 + i;
        float* dst = G + ((size_t)d*M_ + m)*G4H + n0 + tx*4;
        #pragma unroll
        for (int j = 0; j < 4; ++j) {
            const int n = n0 + tx*4 + j;
            dst[j] = acc[i][j] + bb1[n] + bb2[n];
        }
    }
}

// ------------------------------------------------- LSTM recurrence (R5 structure)
// grid 128: d = bid>>6, jb = bid&63 -> hidden units [jb*6, jb*6+6), 24 gate rows.
// R7 deltas vs R5 (address-level only):
//   1) h staging uses lane-major coalesced coherent loads (same hs[32][388] layout)
//   2) G prefetch moved after the flag store (off the vmcnt drain, overlaps poll)
__global__ __launch_bounds__(256) void recur_k(
    const float* __restrict__ G,    // [2][M][1536] pre-gates
    const float* __restrict__ Whh,  // [2][1536][384] (this layer)
    float* __restrict__ Yout,       // [B][L][768]
    float* __restrict__ H,          // [2 parity][2 dir][32][384]
    unsigned* __restrict__ flags)   // [2 dir][64 blocks][32 stride]
{
    const int bid = blockIdx.x;
    const int d  = bid >> 6;
    const int jb = bid & 63;
    const int j0 = jb * 6;
    const int tid = threadIdx.x;
    const int b  = tid >> 3;
    const int rr = tid & 7;
    unsigned* myflag = flags + ((size_t)d*64 + jb)*32;
    const unsigned* dirflags = flags + (size_t)d*64*32;

    __shared__ float w_s[24][388];
    __shared__ float hs[32][388];
    __shared__ float gbuf[32][24];
    __shared__ float c_s[32*6];

    for (int idx = tid; idx < 24*384; idx += 256) {
        const int r = idx / 384, k = idx - r*384;
        const int n = (r/6)*384 + j0 + (r%6);
        w_s[r][k] = Whh[(size_t)d*G4H*HH_ + (size_t)n*HH_ + k];
    }
    if (tid < 192) c_s[tid] = 0.0f;
    __syncthreads();

    const int row0 = rr, row1 = rr+8, row2 = rr+16;
    const int n0 = (row0/6)*384 + j0 + (row0%6);
    const int n1 = (row1/6)*384 + j0 + (row1%6);
    const int n2 = (row2/6)*384 + j0 + (row2%6);

    // t = 0 pre-gates
    const int tt0 = d ? (LSEQ-1) : 0;
    size_t grow = ((size_t)d*M_ + (size_t)b*LSEQ + tt0) * G4H;
    float a0 = G[grow + n0];
    float a1 = G[grow + n1];
    float a2 = G[grow + n2];

    for (int t = 0; t < LSEQ; ++t) {
        if (t > 0) {
            // stage prev h: lane-major coalesced coherent loads (2 L3 lines/inst),
            // scatter to the SAME hs[b][k] layout as R5
            {
                const float* Hdir = H + (size_t)((((t-1)&1)*2 + d)*32)*HH_;
                float tmp[48];
                #pragma unroll
                for (int ii = 0; ii < 48; ++ii) tmp[ii] = ld_coh(Hdir + ii*256 + tid);
                #pragma unroll
                for (int ii = 0; ii < 48; ++ii) {
                    const int g  = ii*256 + tid;
                    const int b2 = g / 384;
                    const int k  = g - b2*384;
                    hs[b2][k] = tmp[ii];
                }
            }
            __syncthreads();   // uniform branch: all threads reach this
            const float* hb = hs[b];
            #pragma unroll 8
            for (int k4 = 0; k4 < 96; ++k4) {
                const float4 h4 = *(const float4*)(hb + (k4<<2));
                const float4 w0 = *(const float4*)(&w_s[row0][k4<<2]);
                const float4 w1 = *(const float4*)(&w_s[row1][k4<<2]);
                const float4 w2 = *(const float4*)(&w_s[row2][k4<<2]);
                a0 = fmaf(h4.x,w0.x,fmaf(h4.y,w0.y,fmaf(h4.z,w0.z,fmaf(h4.w,w0.w,a0))));
                a1 = fmaf(h4.x,w1.x,fmaf(h4.y,w1.y,fmaf(h4.z,w1.z,fmaf(h4.w,w1.w,a1))));
                a2 = fmaf(h4.x,w2.x,fmaf(h4.y,w2.y,fmaf(h4.z,w2.z,fmaf(h4.w,w2.w,a2))));
            }
        }
        gbuf[b][row0] = a0; gbuf[b][row1] = a1; gbuf[b][row2] = a2;
        __syncthreads();

        if (tid < 192) {
            const int bb = tid / 6, jj = tid - (tid/6)*6;
            const float gi = gbuf[bb][jj];
            const float gf = gbuf[bb][6+jj];
            const float gg = gbuf[bb][12+jj];
            const float go = gbuf[bb][18+jj];
            const float c = sigf(gf)*c_s[tid] + sigf(gi)*tanhf(gg);
            const float h = sigf(go)*tanhf(c);
            c_s[tid] = c;
            // coherent (write-through) h publish
            st_coh(&H[((((size_t)(t&1))*2 + d)*32 + bb)*HH_ + j0 + jj], h);
            Yout[((size_t)bb*LSEQ + ((d ? (LSEQ-1-t) : t)))*DD_ + d*HH_ + j0 + jj] = h;
        }

        if (t + 1 < LSEQ) {
            asm volatile("s_waitcnt vmcnt(0)" ::: "memory");  // h stores at L3
            __syncthreads();                                   // whole block drained
            if (tid == 0) stu_coh(myflag, (unsigned)(t + 1));  // arrive (own line)
            {
                // prefetch next step's pre-gates AFTER the drain — overlaps the poll
                const int ttn = d ? (LSEQ-2-t) : (t+1);
                grow = ((size_t)d*M_ + (size_t)b*LSEQ + ttn) * G4H;
                a0 = G[grow + n0];
                a1 = G[grow + n1];
                a2 = G[grow + n2];
            }
            if (tid < 64) {                                    // wave0: distributed wait
                const unsigned* fp = dirflags + tid*32;
                while (ldu_coh(fp) <= (unsigned)t) {
                    __builtin_amdgcn_s_sleep(1);
                }
            }
            __syncthreads();
        }
    }
}

// ------------------------------------------------- compaction scan
__global__ __launch_bounds__(256) void scan_k(
    const int* __restrict__ valid, const int* __restrict__ lmask,
    int* __restrict__ dest, int* __restrict__ nvm)
{
    const int b = blockIdx.x, l = threadIdx.x;
    __shared__ int arr[256];
    __shared__ int ms[256];
    arr[l] = valid[b*256 + l];
    ms[l]  = lmask[b*256 + l];
    __syncthreads();
    for (int off = 1; off < 256; off <<= 1) {
        const int add = arr[l] + ((l >= off) ? arr[l-off] : 0);
        __syncthreads();
        arr[l] = add;
        __syncthreads();
    }
    dest[b*256 + l] = arr[l] - 1;
    for (int off = 128; off; off >>= 1) { if (l < off) ms[l] += ms[l+off]; __syncthreads(); }
    if (l == 0) nvm[b] = ms[0];
}

__global__ __launch_bounds__(256) void scatter_k(
    const int* __restrict__ valid, const int* __restrict__ dest,
    const float* __restrict__ S, float* __restrict__ V)
{
    const int blt = blockIdx.x;
    if (!valid[blt]) return;
    const int b = blt >> 8;
    const int dd = dest[blt];
    const int tid = threadIdx.x;
    const float* src = S + (size_t)blt * DD_;
    float* dst = V + ((size_t)(b*256 + dd)) * DD_;
    dst[tid] = src[tid]; dst[tid+256] = src[tid+256]; dst[tid+512] = src[tid+512];
}

// ------------------------------------------------- heads: logits (wave per row)
__global__ __launch_bounds__(256) void heads_k(
    const float* __restrict__ V,
    const float* __restrict__ pW, const float* __restrict__ pb,
    const float* __restrict__ cW, const float* __restrict__ cb,
    float* __restrict__ PL, float* __restrict__ CL)
{
    const int w = threadIdx.x >> 6, lane = threadIdx.x & 63;
    const int m = blockIdx.x*4 + w;
    const float* vr = V + (size_t)m * DD_;
    float ap[9] = {}; float ac[3] = {};
    #pragma unroll
    for (int kk = 0; kk < 12; ++kk) {
        const int k = kk*64 + lane;
        const float v = vr[k];
        #pragma unroll
        for (int o = 0; o < 9; ++o) ap[o] = fmaf(v, pW[o*DD_ + k], ap[o]);
        #pragma unroll
        for (int o = 0; o < 3; ++o) ac[o] = fmaf(v, cW[o*DD_ + k], ac[o]);
    }
    #pragma unroll
    for (int o = 0; o < 9; ++o) {
        float r = ap[o];
        for (int off = 32; off; off >>= 1) r += __shfl_down(r, off);
        if (lane == 0) PL[(size_t)m*9 + o] = r + pb[o];
    }
    #pragma unroll
    for (int o = 0; o < 3; ++o) {
        float r = ac[o];
        for (int off = 32; off; off >>= 1) r += __shfl_down(r, off);
        if (lane == 0) CL[(size_t)m*3 + o] = r + cb[o];
    }
}

// ------------------------------------------------- CRF log-likelihood (wave per b)
template<int NT>
__global__ __launch_bounds__(64) void crf_ll_k(
    const float* __restrict__ E, const int* __restrict__ tg,
    const int* __restrict__ nvm,
    const float* __restrict__ st, const float* __restrict__ en,
    const float* __restrict__ tr, float* __restrict__ llout)
{
    const int b = blockIdx.x;
    const int lane = threadIdx.x;
    const int nv = nvm[b];
    const int base = b*256;
    float num = 0.0f;
    for (int t = lane; t < nv; t += 64) {
        const int tgt = tg[base + t];
        float c = E[(size_t)(base + t)*NT + tgt];
        if (t > 0) c += tr[tg[base + t - 1]*NT + tgt];
        num += c;
    }
    for (int off = 32; off; off >>= 1) num += __shfl_down(num, off);

    float trc[NT];
    float s;
    if (lane < NT) {
        #pragma unroll
        for (int i = 0; i < NT; ++i) trc[i] = tr[i*NT + lane];
        s = st[lane] + E[(size_t)base*NT + lane];
    } else {
        #pragma unroll
        for (int i = 0; i < NT; ++i) trc[i] = 0.0f;
        s = -INFINITY;
    }
    for (int t = 1; t < nv; ++t) {
        float si[NT];
        #pragma unroll
        for (int i = 0; i < NT; ++i) si[i] = __shfl(s, i) + trc[i];
        float m = si[0];
        #pragma unroll
        for (int i = 1; i < NT; ++i) m = fmaxf(m, si[i]);
        float sum = 0.0f;
        #pragma unroll
        for (int i = 0; i < NT; ++i) sum += expf(si[i] - m);
        if (lane < NT) s = m + logf(sum) + E[(size_t)(base + t)*NT + lane];
    }
    float v = (lane < NT) ? s + en[lane] : -INFINITY;
    float mx = v;
    for (int off = 32; off; off >>= 1) mx = fmaxf(mx, __shfl_xor(mx, off));
    float ex = (lane < NT) ? expf(v - mx) : 0.0f;
    for (int off = 32; off; off >>= 1) ex += __shfl_xor(ex, off);
    const float logZ = mx + logf(ex);
    if (lane == 0) {
        num += st[tg[base]] + en[tg[base + nv - 1]];
        llout[b] = num - logZ;
    }
}

// ------------------------------------------------- Viterbi decode (wave per b)
template<int NT>
__global__ __launch_bounds__(64) void viterbi_k(
    const float* __restrict__ E, const int* __restrict__ nvm,
    const float* __restrict__ st, const float* __restrict__ en,
    const float* __restrict__ tr, float* __restrict__ outp)
{
    const int b = blockIdx.x;
    const int lane = threadIdx.x;
    const int nv = nvm[b];
    const int base = b*256;
    float* o = outp + base;
    __shared__ unsigned char hist[256][16];
    float trc[NT];
    float s;
    if (lane < NT) {
        #pragma unroll
        for (int i = 0; i < NT; ++i) trc[i] = tr[i*NT + lane];
        s = st[lane] + E[(size_t)base*NT + lane];
    } else {
        #pragma unroll
        for (int i = 0; i < NT; ++i) trc[i] = 0.0f;
        s = -INFINITY;
    }
    for (int t = 1; t < nv; ++t) {
        float si[NT];
        #pragma unroll
        for (int i = 0; i < NT; ++i) si[i] = __shfl(s, i) + trc[i];
        float best = si[0];
        int bi = 0;
        #pragma unroll
        for (int i = 1; i < NT; ++i) if (si[i] > best) { best = si[i]; bi = i; }
        if (lane < NT) {
            hist[t][lane] = (unsigned char)bi;
            s = best + E[(size_t)(base + t)*NT + lane];
        }
    }
    float v = (lane < NT) ? s + en[lane] : -INFINITY;
    int idx = lane;
    for (int off = 32; off; off >>= 1) {
        const float ov = __shfl_xor(v, off);
        const int   oi = __shfl_xor(idx, off);
        if (ov > v || (ov == v && oi < idx)) { v = ov; idx = oi; }
    }
    __syncthreads();
    if (lane == 0) {
        int tag = idx;
        o[nv-1] = (float)tag;
        for (int t = nv - 1; t >= 1; --t) {
            tag = hist[t][tag];
            o[t-1] = (float)tag;
        }
    }
    for (int t = nv + lane; t < 256; t += 64) o[t] = 0.0f;
}

__global__ __launch_bounds__(64) void finalize_k(const float* __restrict__ llb,
                                                 float* __restrict__ out)
{
    const int lane = threadIdx.x;
    const float v = llb[lane];
    float p = (lane < 32) ? v : 0.0f;
    float c = (lane < 32) ? 0.0f : v;
    for (int off = 32; off; off >>= 1) { p += __shfl_down(p, off); c += __shfl_down(c, off); }
    if (lane == 0) { out[0] = -(p + c); out[1] = p; out[2] = c; }
}

// ================================================================ host
extern "C" void kernel_launch(void* const* d_in, const int* in_sizes, int n_in,
                              void* d_out, int out_size, void* d_ws, size_t ws_size,
                              hipStream_t stream) {
    const int*   input_ids = (const int*)d_in[0];
    const int*   tt_ids    = (const int*)d_in[1];
    const int*   valid     = (const int*)d_in[2];
    const int*   plab      = (const int*)d_in[3];
    const int*   clab      = (const int*)d_in[4];
    const int*   lmask     = (const int*)d_in[5];
    const float* wemb      = (const float*)d_in[6];
    const float* pemb      = (const float*)d_in[7];
    const float* temb      = (const float*)d_in[8];
    const float* ln_g      = (const float*)d_in[9];
    const float* ln_b      = (const float*)d_in[10];
    const float* Wih       = (const float*)d_in[11];
    const float* Whh       = (const float*)d_in[12];
    const float* bih       = (const float*)d_in[13];
    const float* bhh       = (const float*)d_in[14];
    const float* pW        = (const float*)d_in[15];
    const float* pb        = (const float*)d_in[16];
    const float* cW        = (const float*)d_in[17];
    const float* cb        = (const float*)d_in[18];
    const float* p_start   = (const float*)d_in[19];
    const float* p_end     = (const float*)d_in[20];
    const float* p_trans   = (const float*)d_in[21];
    const float* c_start   = (const float*)d_in[22];
    const float* c_end     = (const float*)d_in[23];
    const float* c_trans   = (const float*)d_in[24];

    float* ws = (float*)d_ws;
    float* X   = ws;                       // 6,291,456
    float* Y   = X  + 6291456;             // 6,291,456
    float* Gb  = Y  + 6291456;             // 25,165,824
    float* V   = Gb + 25165824;            // 6,291,456
    float* PL  = V  + 6291456;             // 73,728
    float* CL  = PL + 73728;               // 24,576
    float* Hb  = CL + 24576;               // 98,304
    float* llb = Hb + 98304;               // 64
    int*   destb = (int*)(llb + 64);       // 8192 ints
    int*   nvm   = destb + 8192;           // 32 ints
    unsigned* flags = (unsigned*)(nvm + 32); // [2 layer][2 dir][64][32] u32
    float* out = (float*)d_out;

    embed_ln_k<<<8192, 256, 0, stream>>>(input_ids, tt_ids, wemb, pemb, temb, ln_g, ln_b, X);
    hipMemsetAsync(flags, 0, 16384 * sizeof(unsigned), stream);

    for (int layer = 0; layer < 2; ++layer) {
        const float* Xin  = layer ? Y : X;
        float*       Yout = layer ? X : Y;
        const float* Wl  = Wih + (size_t)layer * 2 * G4H * DD_;
        const float* Whl = Whh + (size_t)layer * 2 * G4H * HH_;
        const float* b1  = bih + (size_t)layer * 2 * G4H;
        const float* b2  = bhh + (size_t)layer * 2 * G4H;
        gemm_xw_k<<<dim3(64, 24, 2), 256, 0, stream>>>(Xin, Wl, b1, b2, Gb);
        const float* gA = Gb; const float* wA = Whl; float* yA = Yout; float* hA = Hb;
        unsigned* flA = flags + (size_t)layer * 2 * 64 * 32;
        void* kargs[] = { (void*)&gA, (void*)&wA, (void*)&yA, (void*)&hA, (void*)&flA };
        hipLaunchCooperativeKernel((const void*)recur_k, dim3(128), dim3(256), kargs, 0, stream);
    }

    scan_k<<<32, 256, 0, stream>>>(valid, lmask, destb, nvm);
    hipMemsetAsync(V, 0, (size_t)6291456 * 4, stream);
    scatter_k<<<8192, 256, 0, stream>>>(valid, destb, X, V);   // final seq is in X
    heads_k<<<2048, 256, 0, stream>>>(V, pW, pb, cW, cb, PL, CL);

    crf_ll_k<9><<<32, 64, 0, stream>>>(PL, plab, nvm, p_start, p_end, p_trans, llb);
    crf_ll_k<3><<<32, 64, 0, stream>>>(CL, clab, nvm, c_start, c_end, c_trans, llb + 32);
    viterbi_k<9><<<32, 64, 0, stream>>>(PL, nvm, p_start, p_end, p_trans, out + 3);
    viterbi_k<3><<<32, 64, 0, stream>>>(CL, nvm, c_start, c_end, c_trans, out + 3 + 8192);
    finalize_k<<<1, 64, 0, stream>>>(llb, out);
}